// Round 6
// baseline (473.363 us; speedup 1.0000x reference)
//
#include <hip/hip_runtime.h>

#define N_NODES 50000
#define N_EDGES 800000
#define DIM 128
#define NLAYERS 3
#define NGRAPH 512
#define SCAN_NB ((N_NODES + 255) / 256)   // 196

typedef __attribute__((ext_vector_type(8)))  __bf16 bf16x8;
typedef __attribute__((ext_vector_type(16))) float  f32x16;

// ---------------------------------------------------------------- fp32 -> bf16 cast
__global__ __launch_bounds__(256) void k_cast(const float* __restrict__ in,
                                              __bf16* __restrict__ out, int n) {
    int i = blockIdx.x * blockDim.x + threadIdx.x;
    int base = i * 8;
    if (base >= n) return;
    float4 a = *(const float4*)(in + base);
    float4 b = *(const float4*)(in + base + 4);
    bf16x8 o;
    o[0] = (__bf16)a.x; o[1] = (__bf16)a.y; o[2] = (__bf16)a.z; o[3] = (__bf16)a.w;
    o[4] = (__bf16)b.x; o[5] = (__bf16)b.y; o[6] = (__bf16)b.z; o[7] = (__bf16)b.w;
    *(bf16x8*)(out + base) = o;
}

// 4 weight tensors in one launch (blockIdx.y selects)
__global__ __launch_bounds__(256) void k_cast4(
    const float* __restrict__ i0, const float* __restrict__ i1,
    const float* __restrict__ i2, const float* __restrict__ i3,
    __bf16* __restrict__ o0, __bf16* __restrict__ o1,
    __bf16* __restrict__ o2, __bf16* __restrict__ o3, int n) {
    int sel = blockIdx.y;
    const float* in = (sel == 0) ? i0 : (sel == 1) ? i1 : (sel == 2) ? i2 : i3;
    __bf16* out     = (sel == 0) ? o0 : (sel == 1) ? o1 : (sel == 2) ? o2 : o3;
    int i = blockIdx.x * blockDim.x + threadIdx.x;
    int base = i * 8;
    if (base >= n) return;
    float4 a = *(const float4*)(in + base);
    float4 b = *(const float4*)(in + base + 4);
    bf16x8 o;
    o[0] = (__bf16)a.x; o[1] = (__bf16)a.y; o[2] = (__bf16)a.z; o[3] = (__bf16)a.w;
    o[4] = (__bf16)b.x; o[5] = (__bf16)b.y; o[6] = (__bf16)b.z; o[7] = (__bf16)b.w;
    *(bf16x8*)(out + base) = o;
}

// ---------------------------------------------------------------- degree
__global__ __launch_bounds__(256) void k_degree(const int* __restrict__ dst,
                                                int* __restrict__ cnt) {
    int i = blockIdx.x * blockDim.x + threadIdx.x;
    if (i < N_EDGES) atomicAdd(&cnt[dst[i]], 1);
}

// ---------------------------------------------------------------- hierarchical scan
__global__ __launch_bounds__(256) void k_scan1(const int* __restrict__ cnt,
                                               int* __restrict__ off,
                                               int* __restrict__ bsum) {
    __shared__ int s[256];
    int b = blockIdx.x, t = threadIdx.x;
    int i = b * 256 + t;
    int v = (i < N_NODES) ? cnt[i] : 0;
    s[t] = v; __syncthreads();
#pragma unroll
    for (int d = 1; d < 256; d <<= 1) {
        int nv = (t >= d) ? s[t - d] : 0;
        __syncthreads();
        s[t] += nv;
        __syncthreads();
    }
    if (i < N_NODES) off[i] = s[t] - v;
    if (t == 255) bsum[b] = s[255];
}

__global__ __launch_bounds__(256) void k_scan2(const int* __restrict__ bsum,
                                               int* __restrict__ boff,
                                               int* __restrict__ offN) {
    __shared__ int s[256];
    int t = threadIdx.x;
    int v = (t < SCAN_NB) ? bsum[t] : 0;
    s[t] = v; __syncthreads();
#pragma unroll
    for (int d = 1; d < 256; d <<= 1) {
        int nv = (t >= d) ? s[t - d] : 0;
        __syncthreads();
        s[t] += nv;
        __syncthreads();
    }
    boff[t] = s[t] - v;
    if (t == 255) *offN = s[255];
}

__global__ __launch_bounds__(256) void k_scan3(int* __restrict__ off,
                                               const int* __restrict__ boff) {
    int b = blockIdx.x, t = threadIdx.x;
    int i = b * 256 + t;
    if (i < N_NODES) off[i] += boff[b];
}

// ---------------------------------------------------------------- scatter to CSR (src only)
__global__ __launch_bounds__(256) void k_scatter(const int* __restrict__ src,
                                                 const int* __restrict__ dst,
                                                 const int* __restrict__ off,
                                                 int* __restrict__ cursor,
                                                 int* __restrict__ src_s) {
    int i = blockIdx.x * blockDim.x + threadIdx.x;
    if (i < N_EDGES) {
        int d = dst[i];
        int pos = off[d] + atomicAdd(&cursor[d], 1);
        src_s[pos] = src[i];
    }
}

// ---------------------------------------------------------------- MFMA GEMM: out = X @ W.T + b
__global__ __launch_bounds__(256) void k_gemm_mfma(
    const __bf16* __restrict__ Xb,
    const __bf16* __restrict__ Wq, const __bf16* __restrict__ Wk,
    const __bf16* __restrict__ Wv, const __bf16* __restrict__ Wsk,
    const float* __restrict__ Bq, const float* __restrict__ Bk,
    const float* __restrict__ Bv, const float* __restrict__ Bs,
    __bf16* __restrict__ Oq, __bf16* __restrict__ Okv,
    float* __restrict__ Osk) {
    const int wsel = blockIdx.y;
    const __bf16* W = (wsel == 0) ? Wq : (wsel == 1) ? Wk : (wsel == 2) ? Wv : Wsk;
    const float*  B = (wsel == 0) ? Bq : (wsel == 1) ? Bk : (wsel == 2) ? Bv : Bs;

    int t = threadIdx.x;
    int wave = t >> 6, l = t & 63;
    int lo5 = l & 31, hi = l >> 5;
    int row0 = blockIdx.x * 32;
    int col0 = wave * 32;

    const bf16x8* arow = (const bf16x8*)(Xb + (size_t)(row0 + lo5) * DIM + hi * 8);
    const bf16x8* brow = (const bf16x8*)(W  + (size_t)(col0 + lo5) * DIM + hi * 8);

    f32x16 acc = {};
#pragma unroll
    for (int kt = 0; kt < 8; ++kt)
        acc = __builtin_amdgcn_mfma_f32_32x32x16_bf16(arow[kt * 2], brow[kt * 2], acc, 0, 0, 0);

    float bias = B[col0 + lo5];
    if (wsel == 3) {
#pragma unroll
        for (int r = 0; r < 16; ++r) {
            int row = row0 + (r & 3) + 8 * (r >> 2) + 4 * hi;
            if (row < N_NODES)
                Osk[(size_t)row * DIM + col0 + lo5] = acc[r] + bias;
        }
    } else {
        __bf16* O; size_t stride; int coff;
        if (wsel == 0) { O = Oq;  stride = DIM;     coff = 0; }
        else           { O = Okv; stride = 2 * DIM; coff = (wsel == 2) ? DIM : 0; }
#pragma unroll
        for (int r = 0; r < 16; ++r) {
            int row = row0 + (r & 3) + 8 * (r >> 2) + 4 * hi;
            if (row < N_NODES)
                O[(size_t)row * stride + coff + col0 + lo5] = (__bf16)(acc[r] + bias);
        }
    }
}

// ---------------------------------------------------------------- fused alpha + softmax + aggregate (+skip+relu)
// One 16-lane group per node (4 nodes/wave, 16/block). Defer-max online softmax
// (rescale only when p > m+4), 2-edge unroll for MLP. No cross-group merge.
__global__ __launch_bounds__(256) void k_edge_fused(const __bf16* __restrict__ q,
                                                    const __bf16* __restrict__ kv,
                                                    const float* __restrict__ skip,
                                                    const int* __restrict__ src_s,
                                                    const int* __restrict__ off,
                                                    float* __restrict__ xout,
                                                    __bf16* __restrict__ xb) {
    int t = threadIdx.x;
    int l = t & 63;
    int g = l >> 4, gl = l & 15;                 // 4 groups of 16 lanes
    int n = blockIdx.x * 16 + (t >> 6) * 4 + g;  // 16 nodes per block (50000 = 3125*16)
    if (n >= N_NODES) return;
    int start = off[n], end = off[n + 1];

    // q fragment: 8 dims per lane, fp32
    float qf[8];
    {
        bf16x8 qv = *(const bf16x8*)(q + (size_t)n * DIM + gl * 8);
#pragma unroll
        for (int j = 0; j < 8; ++j) qf[j] = (float)qv[j];
    }

    float m = -INFINITY, denom = 0.f;
    float facc[8] = {};

    for (int e = start; e < end; e += 2) {
        bool has1 = (e + 1 < end);
        int s0 = src_s[e];
        int s1 = has1 ? src_s[e + 1] : s0;       // dummy (w1 forced to 0)
        const bf16x8* r0 = (const bf16x8*)(kv + (size_t)s0 * (2 * DIM) + gl * 8);
        const bf16x8* r1 = (const bf16x8*)(kv + (size_t)s1 * (2 * DIM) + gl * 8);
        bf16x8 k0 = r0[0], v0 = r0[16];          // v at +128 elems
        bf16x8 k1 = r1[0], v1 = r1[16];

        float p0 = 0.f, p1 = 0.f;
#pragma unroll
        for (int j = 0; j < 8; ++j) p0 += qf[j] * (float)k0[j];
#pragma unroll
        for (int j = 0; j < 8; ++j) p1 += qf[j] * (float)k1[j];
        p0 += __shfl_xor(p0, 8, 16);  p1 += __shfl_xor(p1, 8, 16);
        p0 += __shfl_xor(p0, 4, 16);  p1 += __shfl_xor(p1, 4, 16);
        p0 += __shfl_xor(p0, 2, 16);  p1 += __shfl_xor(p1, 2, 16);
        p0 += __shfl_xor(p0, 1, 16);  p1 += __shfl_xor(p1, 1, 16);
        p0 *= 0.08838834764831845f;
        p1 = has1 ? p1 * 0.08838834764831845f : -INFINITY;

        float pm = fmaxf(p0, p1);
        if (pm > m + 4.f) {                      // rare: deferred rescale
            float sc = __expf(m - pm);           // 0 on first edge
            denom *= sc;
#pragma unroll
            for (int j = 0; j < 8; ++j) facc[j] *= sc;
            m = pm;
        }
        float w0 = __expf(p0 - m);               // bounded by e^4
        float w1 = has1 ? __expf(p1 - m) : 0.f;
        denom += w0 + w1;
#pragma unroll
        for (int j = 0; j < 8; ++j)
            facc[j] += w0 * (float)v0[j] + w1 * (float)v1[j];
    }

    float inv = (denom > 0.f) ? 1.f / denom : 0.f;

    // epilogue: skip + relu, fp32 out + bf16 shadow (per-lane 8 dims)
    const float* skrow = skip + (size_t)n * DIM + gl * 8;
    float4 s4a = *(const float4*)(skrow);
    float4 s4b = *(const float4*)(skrow + 4);
    float o[8] = { s4a.x, s4a.y, s4a.z, s4a.w, s4b.x, s4b.y, s4b.z, s4b.w };
    bf16x8 ob;
#pragma unroll
    for (int j = 0; j < 8; ++j) {
        float val = fmaxf(o[j] + facc[j] * inv, 0.f);
        o[j] = val; ob[j] = (__bf16)val;
    }
    float* xrow = xout + (size_t)n * DIM + gl * 8;
    *(float4*)(xrow)     = make_float4(o[0], o[1], o[2], o[3]);
    *(float4*)(xrow + 4) = make_float4(o[4], o[5], o[6], o[7]);
    *(bf16x8*)(xb + (size_t)n * DIM + gl * 8) = ob;
}

// ---------------------------------------------------------------- mean pool
__global__ __launch_bounds__(256) void k_pool(const float* __restrict__ x,
                                              const int* __restrict__ batch,
                                              float* __restrict__ out) {
    __shared__ float sacc[4][DIM];
    int g = blockIdx.x;
    int t = threadIdx.x;
    int w = t >> 6, l = t & 63;
    int lo = 0, hi = N_NODES;
    while (lo < hi) { int mid = (lo + hi) >> 1; if (batch[mid] < g) lo = mid + 1; else hi = mid; }
    int s0 = lo;
    hi = N_NODES;
    while (lo < hi) { int mid = (lo + hi) >> 1; if (batch[mid] < g + 1) lo = mid + 1; else hi = mid; }
    int s1 = lo;
    float a0 = 0.f, a1 = 0.f;
    for (int n = s0 + w; n < s1; n += 4) {
        float2 xr = *(const float2*)(x + (size_t)n * DIM + l * 2);
        a0 += xr.x; a1 += xr.y;
    }
    sacc[w][l * 2] = a0; sacc[w][l * 2 + 1] = a1;
    __syncthreads();
    if (t < DIM) {
        float s = sacc[0][t] + sacc[1][t] + sacc[2][t] + sacc[3][t];
        int cnt = s1 - s0;
        out[(size_t)g * DIM + t] = s / (float)((cnt > 0) ? cnt : 1);
    }
}

// ----------------------------------------------------------------
extern "C" void kernel_launch(void* const* d_in, const int* in_sizes, int n_in,
                              void* d_out, int out_size, void* d_ws, size_t ws_size,
                              hipStream_t stream) {
    const float* x0   = (const float*)d_in[0];
    const int*  eidx  = (const int*)d_in[1];
    const int*  batch = (const int*)d_in[2];
    const float* Wq = (const float*)d_in[3];
    const float* bq = (const float*)d_in[4];
    const float* Wk = (const float*)d_in[5];
    const float* bk = (const float*)d_in[6];
    const float* Wv = (const float*)d_in[7];
    const float* bv = (const float*)d_in[8];
    const float* Ws = (const float*)d_in[9];
    const float* bs = (const float*)d_in[10];
    float* out = (float*)d_out;

    const int* src = eidx;
    const int* dst = eidx + N_EDGES;

    char* ws = (char*)d_ws;
    size_t p = 0;
    auto alloc = [&](size_t bytes) -> void* {
        void* r = ws + p;
        p = (p + bytes + 255) & ~(size_t)255;
        return r;
    };
    int*    off    = (int*)alloc((N_NODES + 1) * sizeof(int));
    int*    cnt    = (int*)alloc(N_NODES * sizeof(int));
    int*    bsum   = (int*)alloc(256 * sizeof(int));
    int*    boff   = (int*)alloc(256 * sizeof(int));
    int*    src_s  = (int*)alloc(N_EDGES * sizeof(int));
    __bf16* Xb     = (__bf16*)alloc((size_t)N_NODES * DIM * sizeof(__bf16));
    __bf16* qb     = (__bf16*)alloc((size_t)N_NODES * DIM * sizeof(__bf16));
    __bf16* kvb    = (__bf16*)alloc((size_t)N_NODES * 2 * DIM * sizeof(__bf16));
    float*  s1     = (float*)alloc((size_t)N_NODES * DIM * sizeof(float));
    __bf16* Wqb    = (__bf16*)alloc((size_t)NLAYERS * DIM * DIM * sizeof(__bf16));
    __bf16* Wkb    = (__bf16*)alloc((size_t)NLAYERS * DIM * DIM * sizeof(__bf16));
    __bf16* Wvb    = (__bf16*)alloc((size_t)NLAYERS * DIM * DIM * sizeof(__bf16));
    __bf16* Wsb    = (__bf16*)alloc((size_t)NLAYERS * DIM * DIM * sizeof(__bf16));

    // ---- casts
    {
        int nx = N_NODES * DIM;
        k_cast<<<(nx / 8 + 255) / 256, 256, 0, stream>>>(x0, Xb, nx);
        int nw = NLAYERS * DIM * DIM;
        dim3 gw((nw / 8 + 255) / 256, 4);
        k_cast4<<<gw, 256, 0, stream>>>(Wq, Wk, Wv, Ws, Wqb, Wkb, Wvb, Wsb, nw);
    }

    // ---- build CSR
    hipMemsetAsync(cnt, 0, N_NODES * sizeof(int), stream);
    k_degree<<<(N_EDGES + 255) / 256, 256, 0, stream>>>(dst, cnt);
    k_scan1<<<SCAN_NB, 256, 0, stream>>>(cnt, off, bsum);
    k_scan2<<<1, 256, 0, stream>>>(bsum, boff, off + N_NODES);
    k_scan3<<<SCAN_NB, 256, 0, stream>>>(off, boff);
    hipMemsetAsync(cnt, 0, N_NODES * sizeof(int), stream);
    k_scatter<<<(N_EDGES + 255) / 256, 256, 0, stream>>>(src, dst, off, cnt, src_s);

    // ---- layers
    for (int l = 0; l < NLAYERS; ++l) {
        const __bf16* wq = Wqb + (size_t)l * DIM * DIM;
        const __bf16* wk = Wkb + (size_t)l * DIM * DIM;
        const __bf16* wv = Wvb + (size_t)l * DIM * DIM;
        const __bf16* wsk = Wsb + (size_t)l * DIM * DIM;
        const float* biq = bq + (size_t)l * DIM;
        const float* bik = bk + (size_t)l * DIM;
        const float* biv = bv + (size_t)l * DIM;
        const float* bis = bs + (size_t)l * DIM;

        dim3 ggrid((N_NODES + 31) / 32, 4);
        k_gemm_mfma<<<ggrid, 256, 0, stream>>>(Xb, wq, wk, wv, wsk,
                                               biq, bik, biv, bis,
                                               qb, kvb, s1);
        k_edge_fused<<<(N_NODES + 15) / 16, 256, 0, stream>>>(qb, kvb, s1, src_s, off, s1, Xb);
    }

    // ---- mean pool
    k_pool<<<NGRAPH, 256, 0, stream>>>(s1, batch, out);
}

// Round 7
// 460.535 us; speedup vs baseline: 1.0279x; 1.0279x over previous
//
#include <hip/hip_runtime.h>

#define N_NODES 50000
#define N_EDGES 800000
#define DIM 128
#define NLAYERS 3
#define NGRAPH 512
#define SCAN_NB ((N_NODES + 255) / 256)   // 196

typedef __attribute__((ext_vector_type(8)))  __bf16 bf16x8;
typedef __attribute__((ext_vector_type(16))) float  f32x16;

// ---------------------------------------------------------------- fp32 -> bf16 cast
__global__ __launch_bounds__(256) void k_cast(const float* __restrict__ in,
                                              __bf16* __restrict__ out, int n) {
    int i = blockIdx.x * blockDim.x + threadIdx.x;
    int base = i * 8;
    if (base >= n) return;
    float4 a = *(const float4*)(in + base);
    float4 b = *(const float4*)(in + base + 4);
    bf16x8 o;
    o[0] = (__bf16)a.x; o[1] = (__bf16)a.y; o[2] = (__bf16)a.z; o[3] = (__bf16)a.w;
    o[4] = (__bf16)b.x; o[5] = (__bf16)b.y; o[6] = (__bf16)b.z; o[7] = (__bf16)b.w;
    *(bf16x8*)(out + base) = o;
}

// 4 weight tensors in one launch (blockIdx.y selects)
__global__ __launch_bounds__(256) void k_cast4(
    const float* __restrict__ i0, const float* __restrict__ i1,
    const float* __restrict__ i2, const float* __restrict__ i3,
    __bf16* __restrict__ o0, __bf16* __restrict__ o1,
    __bf16* __restrict__ o2, __bf16* __restrict__ o3, int n) {
    int sel = blockIdx.y;
    const float* in = (sel == 0) ? i0 : (sel == 1) ? i1 : (sel == 2) ? i2 : i3;
    __bf16* out     = (sel == 0) ? o0 : (sel == 1) ? o1 : (sel == 2) ? o2 : o3;
    int i = blockIdx.x * blockDim.x + threadIdx.x;
    int base = i * 8;
    if (base >= n) return;
    float4 a = *(const float4*)(in + base);
    float4 b = *(const float4*)(in + base + 4);
    bf16x8 o;
    o[0] = (__bf16)a.x; o[1] = (__bf16)a.y; o[2] = (__bf16)a.z; o[3] = (__bf16)a.w;
    o[4] = (__bf16)b.x; o[5] = (__bf16)b.y; o[6] = (__bf16)b.z; o[7] = (__bf16)b.w;
    *(bf16x8*)(out + base) = o;
}

// ---------------------------------------------------------------- degree
__global__ __launch_bounds__(256) void k_degree(const int* __restrict__ dst,
                                                int* __restrict__ cnt) {
    int i = blockIdx.x * blockDim.x + threadIdx.x;
    if (i < N_EDGES) atomicAdd(&cnt[dst[i]], 1);
}

// ---------------------------------------------------------------- hierarchical scan
__global__ __launch_bounds__(256) void k_scan1(const int* __restrict__ cnt,
                                               int* __restrict__ off,
                                               int* __restrict__ bsum) {
    __shared__ int s[256];
    int b = blockIdx.x, t = threadIdx.x;
    int i = b * 256 + t;
    int v = (i < N_NODES) ? cnt[i] : 0;
    s[t] = v; __syncthreads();
#pragma unroll
    for (int d = 1; d < 256; d <<= 1) {
        int nv = (t >= d) ? s[t - d] : 0;
        __syncthreads();
        s[t] += nv;
        __syncthreads();
    }
    if (i < N_NODES) off[i] = s[t] - v;
    if (t == 255) bsum[b] = s[255];
}

__global__ __launch_bounds__(256) void k_scan2(const int* __restrict__ bsum,
                                               int* __restrict__ boff,
                                               int* __restrict__ offN) {
    __shared__ int s[256];
    int t = threadIdx.x;
    int v = (t < SCAN_NB) ? bsum[t] : 0;
    s[t] = v; __syncthreads();
#pragma unroll
    for (int d = 1; d < 256; d <<= 1) {
        int nv = (t >= d) ? s[t - d] : 0;
        __syncthreads();
        s[t] += nv;
        __syncthreads();
    }
    boff[t] = s[t] - v;
    if (t == 255) *offN = s[255];
}

__global__ __launch_bounds__(256) void k_scan3(int* __restrict__ off,
                                               const int* __restrict__ boff) {
    int b = blockIdx.x, t = threadIdx.x;
    int i = b * 256 + t;
    if (i < N_NODES) off[i] += boff[b];
}

// ---------------------------------------------------------------- scatter to CSR (src only)
__global__ __launch_bounds__(256) void k_scatter(const int* __restrict__ src,
                                                 const int* __restrict__ dst,
                                                 const int* __restrict__ off,
                                                 int* __restrict__ cursor,
                                                 int* __restrict__ src_s) {
    int i = blockIdx.x * blockDim.x + threadIdx.x;
    if (i < N_EDGES) {
        int d = dst[i];
        int pos = off[d] + atomicAdd(&cursor[d], 1);
        src_s[pos] = src[i];
    }
}

// ---------------------------------------------------------------- MFMA GEMM: out = X @ W.T + b
__global__ __launch_bounds__(256) void k_gemm_mfma(
    const __bf16* __restrict__ Xb,
    const __bf16* __restrict__ Wq, const __bf16* __restrict__ Wk,
    const __bf16* __restrict__ Wv, const __bf16* __restrict__ Wsk,
    const float* __restrict__ Bq, const float* __restrict__ Bk,
    const float* __restrict__ Bv, const float* __restrict__ Bs,
    __bf16* __restrict__ Oq, __bf16* __restrict__ Okv,
    float* __restrict__ Osk) {
    const int wsel = blockIdx.y;
    const __bf16* W = (wsel == 0) ? Wq : (wsel == 1) ? Wk : (wsel == 2) ? Wv : Wsk;
    const float*  B = (wsel == 0) ? Bq : (wsel == 1) ? Bk : (wsel == 2) ? Bv : Bs;

    int t = threadIdx.x;
    int wave = t >> 6, l = t & 63;
    int lo5 = l & 31, hi = l >> 5;
    int row0 = blockIdx.x * 32;
    int col0 = wave * 32;

    const bf16x8* arow = (const bf16x8*)(Xb + (size_t)(row0 + lo5) * DIM + hi * 8);
    const bf16x8* brow = (const bf16x8*)(W  + (size_t)(col0 + lo5) * DIM + hi * 8);

    f32x16 acc = {};
#pragma unroll
    for (int kt = 0; kt < 8; ++kt)
        acc = __builtin_amdgcn_mfma_f32_32x32x16_bf16(arow[kt * 2], brow[kt * 2], acc, 0, 0, 0);

    float bias = B[col0 + lo5];
    if (wsel == 3) {
#pragma unroll
        for (int r = 0; r < 16; ++r) {
            int row = row0 + (r & 3) + 8 * (r >> 2) + 4 * hi;
            if (row < N_NODES)
                Osk[(size_t)row * DIM + col0 + lo5] = acc[r] + bias;
        }
    } else {
        __bf16* O; size_t stride; int coff;
        if (wsel == 0) { O = Oq;  stride = DIM;     coff = 0; }
        else           { O = Okv; stride = 2 * DIM; coff = (wsel == 2) ? DIM : 0; }
#pragma unroll
        for (int r = 0; r < 16; ++r) {
            int row = row0 + (r & 3) + 8 * (r >> 2) + 4 * hi;
            if (row < N_NODES)
                O[(size_t)row * stride + coff + col0 + lo5] = (__bf16)(acc[r] + bias);
        }
    }
}

// ---------------------------------------------------------------- fused alpha + softmax + aggregate (+skip+relu)
// One 16-lane group per node; 4-edge unroll => 8 gathers in flight per group.
// Defer-max online softmax (rescale only when pm > m+4). fp32 out optional.
__global__ __launch_bounds__(256) void k_edge_fused(const __bf16* __restrict__ q,
                                                    const __bf16* __restrict__ kv,
                                                    const float* __restrict__ skip,
                                                    const int* __restrict__ src_s,
                                                    const int* __restrict__ off,
                                                    float* __restrict__ xout,
                                                    __bf16* __restrict__ xb,
                                                    int wf32) {
    int t = threadIdx.x;
    int l = t & 63;
    int g = l >> 4, gl = l & 15;                 // 4 groups of 16 lanes
    int n = blockIdx.x * 16 + (t >> 6) * 4 + g;  // 16 nodes per block
    if (n >= N_NODES) return;
    int start = off[n], end = off[n + 1];

    // q fragment: 8 dims per lane, fp32
    float qf[8];
    {
        bf16x8 qv = *(const bf16x8*)(q + (size_t)n * DIM + gl * 8);
#pragma unroll
        for (int j = 0; j < 8; ++j) qf[j] = (float)qv[j];
    }

    float m = -INFINITY, denom = 0.f;
    float facc[8] = {};
    const float S = 0.08838834764831845f;        // 1/sqrt(128)

    for (int e = start; e < end; e += 4) {
        bool h1 = (e + 1 < end), h2 = (e + 2 < end), h3 = (e + 3 < end);
        int s0 = src_s[e];
        int s1 = h1 ? src_s[e + 1] : s0;
        int s2 = h2 ? src_s[e + 2] : s0;
        int s3 = h3 ? src_s[e + 3] : s0;
        const bf16x8* r0 = (const bf16x8*)(kv + (size_t)s0 * (2 * DIM) + gl * 8);
        const bf16x8* r1 = (const bf16x8*)(kv + (size_t)s1 * (2 * DIM) + gl * 8);
        const bf16x8* r2 = (const bf16x8*)(kv + (size_t)s2 * (2 * DIM) + gl * 8);
        const bf16x8* r3 = (const bf16x8*)(kv + (size_t)s3 * (2 * DIM) + gl * 8);
        bf16x8 k0 = r0[0],  k1 = r1[0],  k2 = r2[0],  k3 = r3[0];
        bf16x8 v0 = r0[16], v1 = r1[16], v2 = r2[16], v3 = r3[16];  // v at +128 elems

        float p0 = 0.f, p1 = 0.f, p2 = 0.f, p3 = 0.f;
#pragma unroll
        for (int j = 0; j < 8; ++j) {
            p0 += qf[j] * (float)k0[j];
            p1 += qf[j] * (float)k1[j];
            p2 += qf[j] * (float)k2[j];
            p3 += qf[j] * (float)k3[j];
        }
        p0 += __shfl_xor(p0, 8, 16); p1 += __shfl_xor(p1, 8, 16);
        p2 += __shfl_xor(p2, 8, 16); p3 += __shfl_xor(p3, 8, 16);
        p0 += __shfl_xor(p0, 4, 16); p1 += __shfl_xor(p1, 4, 16);
        p2 += __shfl_xor(p2, 4, 16); p3 += __shfl_xor(p3, 4, 16);
        p0 += __shfl_xor(p0, 2, 16); p1 += __shfl_xor(p1, 2, 16);
        p2 += __shfl_xor(p2, 2, 16); p3 += __shfl_xor(p3, 2, 16);
        p0 += __shfl_xor(p0, 1, 16); p1 += __shfl_xor(p1, 1, 16);
        p2 += __shfl_xor(p2, 1, 16); p3 += __shfl_xor(p3, 1, 16);
        p0 *= S;
        p1 = h1 ? p1 * S : -INFINITY;
        p2 = h2 ? p2 * S : -INFINITY;
        p3 = h3 ? p3 * S : -INFINITY;

        float pm = fmaxf(fmaxf(p0, p1), fmaxf(p2, p3));
        if (pm > m + 4.f) {                      // rare after first few edges
            float sc = __expf(m - pm);           // 0 on first iteration (m=-inf)
            denom *= sc;
#pragma unroll
            for (int j = 0; j < 8; ++j) facc[j] *= sc;
            m = pm;
        }
        float w0 = __expf(p0 - m);               // bounded by e^4
        float w1 = __expf(p1 - m);               // exp(-inf)=0 kills tail lanes
        float w2 = __expf(p2 - m);
        float w3 = __expf(p3 - m);
        denom += (w0 + w1) + (w2 + w3);
#pragma unroll
        for (int j = 0; j < 8; ++j)
            facc[j] += (w0 * (float)v0[j] + w1 * (float)v1[j])
                     + (w2 * (float)v2[j] + w3 * (float)v3[j]);
    }

    float inv = (denom > 0.f) ? 1.f / denom : 0.f;

    // epilogue: skip + relu; bf16 shadow always, fp32 only when needed (last layer)
    const float* skrow = skip + (size_t)n * DIM + gl * 8;
    float4 s4a = *(const float4*)(skrow);
    float4 s4b = *(const float4*)(skrow + 4);
    float o[8] = { s4a.x, s4a.y, s4a.z, s4a.w, s4b.x, s4b.y, s4b.z, s4b.w };
    bf16x8 ob;
#pragma unroll
    for (int j = 0; j < 8; ++j) {
        float val = fmaxf(o[j] + facc[j] * inv, 0.f);
        o[j] = val; ob[j] = (__bf16)val;
    }
    if (wf32) {
        float* xrow = xout + (size_t)n * DIM + gl * 8;
        *(float4*)(xrow)     = make_float4(o[0], o[1], o[2], o[3]);
        *(float4*)(xrow + 4) = make_float4(o[4], o[5], o[6], o[7]);
    }
    *(bf16x8*)(xb + (size_t)n * DIM + gl * 8) = ob;
}

// ---------------------------------------------------------------- mean pool
__global__ __launch_bounds__(256) void k_pool(const float* __restrict__ x,
                                              const int* __restrict__ batch,
                                              float* __restrict__ out) {
    __shared__ float sacc[4][DIM];
    int g = blockIdx.x;
    int t = threadIdx.x;
    int w = t >> 6, l = t & 63;
    int lo = 0, hi = N_NODES;
    while (lo < hi) { int mid = (lo + hi) >> 1; if (batch[mid] < g) lo = mid + 1; else hi = mid; }
    int s0 = lo;
    hi = N_NODES;
    while (lo < hi) { int mid = (lo + hi) >> 1; if (batch[mid] < g + 1) lo = mid + 1; else hi = mid; }
    int s1 = lo;
    float a0 = 0.f, a1 = 0.f;
    for (int n = s0 + w; n < s1; n += 4) {
        float2 xr = *(const float2*)(x + (size_t)n * DIM + l * 2);
        a0 += xr.x; a1 += xr.y;
    }
    sacc[w][l * 2] = a0; sacc[w][l * 2 + 1] = a1;
    __syncthreads();
    if (t < DIM) {
        float s = sacc[0][t] + sacc[1][t] + sacc[2][t] + sacc[3][t];
        int cnt = s1 - s0;
        out[(size_t)g * DIM + t] = s / (float)((cnt > 0) ? cnt : 1);
    }
}

// ----------------------------------------------------------------
extern "C" void kernel_launch(void* const* d_in, const int* in_sizes, int n_in,
                              void* d_out, int out_size, void* d_ws, size_t ws_size,
                              hipStream_t stream) {
    const float* x0   = (const float*)d_in[0];
    const int*  eidx  = (const int*)d_in[1];
    const int*  batch = (const int*)d_in[2];
    const float* Wq = (const float*)d_in[3];
    const float* bq = (const float*)d_in[4];
    const float* Wk = (const float*)d_in[5];
    const float* bk = (const float*)d_in[6];
    const float* Wv = (const float*)d_in[7];
    const float* bv = (const float*)d_in[8];
    const float* Ws = (const float*)d_in[9];
    const float* bs = (const float*)d_in[10];
    float* out = (float*)d_out;

    const int* src = eidx;
    const int* dst = eidx + N_EDGES;

    char* ws = (char*)d_ws;
    size_t p = 0;
    auto alloc = [&](size_t bytes) -> void* {
        void* r = ws + p;
        p = (p + bytes + 255) & ~(size_t)255;
        return r;
    };
    int*    off    = (int*)alloc((N_NODES + 1) * sizeof(int));
    int*    cnt    = (int*)alloc(N_NODES * sizeof(int));
    int*    bsum   = (int*)alloc(256 * sizeof(int));
    int*    boff   = (int*)alloc(256 * sizeof(int));
    int*    src_s  = (int*)alloc(N_EDGES * sizeof(int));
    __bf16* Xb     = (__bf16*)alloc((size_t)N_NODES * DIM * sizeof(__bf16));
    __bf16* qb     = (__bf16*)alloc((size_t)N_NODES * DIM * sizeof(__bf16));
    __bf16* kvb    = (__bf16*)alloc((size_t)N_NODES * 2 * DIM * sizeof(__bf16));
    float*  s1     = (float*)alloc((size_t)N_NODES * DIM * sizeof(float));
    __bf16* Wqb    = (__bf16*)alloc((size_t)NLAYERS * DIM * DIM * sizeof(__bf16));
    __bf16* Wkb    = (__bf16*)alloc((size_t)NLAYERS * DIM * DIM * sizeof(__bf16));
    __bf16* Wvb    = (__bf16*)alloc((size_t)NLAYERS * DIM * DIM * sizeof(__bf16));
    __bf16* Wsb    = (__bf16*)alloc((size_t)NLAYERS * DIM * DIM * sizeof(__bf16));

    // ---- casts
    {
        int nx = N_NODES * DIM;
        k_cast<<<(nx / 8 + 255) / 256, 256, 0, stream>>>(x0, Xb, nx);
        int nw = NLAYERS * DIM * DIM;
        dim3 gw((nw / 8 + 255) / 256, 4);
        k_cast4<<<gw, 256, 0, stream>>>(Wq, Wk, Wv, Ws, Wqb, Wkb, Wvb, Wsb, nw);
    }

    // ---- build CSR
    hipMemsetAsync(cnt, 0, N_NODES * sizeof(int), stream);
    k_degree<<<(N_EDGES + 255) / 256, 256, 0, stream>>>(dst, cnt);
    k_scan1<<<SCAN_NB, 256, 0, stream>>>(cnt, off, bsum);
    k_scan2<<<1, 256, 0, stream>>>(bsum, boff, off + N_NODES);
    k_scan3<<<SCAN_NB, 256, 0, stream>>>(off, boff);
    hipMemsetAsync(cnt, 0, N_NODES * sizeof(int), stream);
    k_scatter<<<(N_EDGES + 255) / 256, 256, 0, stream>>>(src, dst, off, cnt, src_s);

    // ---- layers
    for (int l = 0; l < NLAYERS; ++l) {
        const __bf16* wq = Wqb + (size_t)l * DIM * DIM;
        const __bf16* wk = Wkb + (size_t)l * DIM * DIM;
        const __bf16* wv = Wvb + (size_t)l * DIM * DIM;
        const __bf16* wsk = Wsb + (size_t)l * DIM * DIM;
        const float* biq = bq + (size_t)l * DIM;
        const float* bik = bk + (size_t)l * DIM;
        const float* biv = bv + (size_t)l * DIM;
        const float* bis = bs + (size_t)l * DIM;

        dim3 ggrid((N_NODES + 31) / 32, 4);
        k_gemm_mfma<<<ggrid, 256, 0, stream>>>(Xb, wq, wk, wv, wsk,
                                               biq, bik, biv, bis,
                                               qb, kvb, s1);
        int wf32 = (l == NLAYERS - 1) ? 1 : 0;
        k_edge_fused<<<(N_NODES + 15) / 16, 256, 0, stream>>>(qb, kvb, s1, src_s, off,
                                                              s1, Xb, wf32);
    }

    // ---- mean pool
    k_pool<<<NGRAPH, 256, 0, stream>>>(s1, batch, out);
}

// Round 8
// 450.753 us; speedup vs baseline: 1.0502x; 1.0217x over previous
//
#include <hip/hip_runtime.h>

#define N_NODES 50000
#define N_EDGES 800000
#define DIM 128
#define NLAYERS 3
#define NGRAPH 512
#define SCAN_NB ((N_NODES + 255) / 256)   // 196

typedef __attribute__((ext_vector_type(8)))  __bf16 bf16x8;
typedef __attribute__((ext_vector_type(16))) float  f32x16;

// ---------------------------------------------------------------- fp32 -> bf16 cast
__global__ __launch_bounds__(256) void k_cast(const float* __restrict__ in,
                                              __bf16* __restrict__ out, int n) {
    int i = blockIdx.x * blockDim.x + threadIdx.x;
    int base = i * 8;
    if (base >= n) return;
    float4 a = *(const float4*)(in + base);
    float4 b = *(const float4*)(in + base + 4);
    bf16x8 o;
    o[0] = (__bf16)a.x; o[1] = (__bf16)a.y; o[2] = (__bf16)a.z; o[3] = (__bf16)a.w;
    o[4] = (__bf16)b.x; o[5] = (__bf16)b.y; o[6] = (__bf16)b.z; o[7] = (__bf16)b.w;
    *(bf16x8*)(out + base) = o;
}

// 4 weight tensors in one launch (blockIdx.y selects)
__global__ __launch_bounds__(256) void k_cast4(
    const float* __restrict__ i0, const float* __restrict__ i1,
    const float* __restrict__ i2, const float* __restrict__ i3,
    __bf16* __restrict__ o0, __bf16* __restrict__ o1,
    __bf16* __restrict__ o2, __bf16* __restrict__ o3, int n) {
    int sel = blockIdx.y;
    const float* in = (sel == 0) ? i0 : (sel == 1) ? i1 : (sel == 2) ? i2 : i3;
    __bf16* out     = (sel == 0) ? o0 : (sel == 1) ? o1 : (sel == 2) ? o2 : o3;
    int i = blockIdx.x * blockDim.x + threadIdx.x;
    int base = i * 8;
    if (base >= n) return;
    float4 a = *(const float4*)(in + base);
    float4 b = *(const float4*)(in + base + 4);
    bf16x8 o;
    o[0] = (__bf16)a.x; o[1] = (__bf16)a.y; o[2] = (__bf16)a.z; o[3] = (__bf16)a.w;
    o[4] = (__bf16)b.x; o[5] = (__bf16)b.y; o[6] = (__bf16)b.z; o[7] = (__bf16)b.w;
    *(bf16x8*)(out + base) = o;
}

// ---------------------------------------------------------------- degree
__global__ __launch_bounds__(256) void k_degree(const int* __restrict__ dst,
                                                int* __restrict__ cnt) {
    int i = blockIdx.x * blockDim.x + threadIdx.x;
    if (i < N_EDGES) atomicAdd(&cnt[dst[i]], 1);
}

// ---------------------------------------------------------------- hierarchical scan
__global__ __launch_bounds__(256) void k_scan1(const int* __restrict__ cnt,
                                               int* __restrict__ off,
                                               int* __restrict__ bsum) {
    __shared__ int s[256];
    int b = blockIdx.x, t = threadIdx.x;
    int i = b * 256 + t;
    int v = (i < N_NODES) ? cnt[i] : 0;
    s[t] = v; __syncthreads();
#pragma unroll
    for (int d = 1; d < 256; d <<= 1) {
        int nv = (t >= d) ? s[t - d] : 0;
        __syncthreads();
        s[t] += nv;
        __syncthreads();
    }
    if (i < N_NODES) off[i] = s[t] - v;
    if (t == 255) bsum[b] = s[255];
}

__global__ __launch_bounds__(256) void k_scan2(const int* __restrict__ bsum,
                                               int* __restrict__ boff,
                                               int* __restrict__ offN) {
    __shared__ int s[256];
    int t = threadIdx.x;
    int v = (t < SCAN_NB) ? bsum[t] : 0;
    s[t] = v; __syncthreads();
#pragma unroll
    for (int d = 1; d < 256; d <<= 1) {
        int nv = (t >= d) ? s[t - d] : 0;
        __syncthreads();
        s[t] += nv;
        __syncthreads();
    }
    boff[t] = s[t] - v;
    if (t == 255) *offN = s[255];
}

__global__ __launch_bounds__(256) void k_scan3(int* __restrict__ off,
                                               const int* __restrict__ boff) {
    int b = blockIdx.x, t = threadIdx.x;
    int i = b * 256 + t;
    if (i < N_NODES) off[i] += boff[b];
}

// ---------------------------------------------------------------- scatter to CSR (src only)
__global__ __launch_bounds__(256) void k_scatter(const int* __restrict__ src,
                                                 const int* __restrict__ dst,
                                                 const int* __restrict__ off,
                                                 int* __restrict__ cursor,
                                                 int* __restrict__ src_s) {
    int i = blockIdx.x * blockDim.x + threadIdx.x;
    if (i < N_EDGES) {
        int d = dst[i];
        int pos = off[d] + atomicAdd(&cursor[d], 1);
        src_s[pos] = src[i];
    }
}

// ---------------------------------------------------------------- MFMA GEMM: out = X @ W.T + b
__global__ __launch_bounds__(256) void k_gemm_mfma(
    const __bf16* __restrict__ Xb,
    const __bf16* __restrict__ Wq, const __bf16* __restrict__ Wk,
    const __bf16* __restrict__ Wv, const __bf16* __restrict__ Wsk,
    const float* __restrict__ Bq, const float* __restrict__ Bk,
    const float* __restrict__ Bv, const float* __restrict__ Bs,
    __bf16* __restrict__ Oq, __bf16* __restrict__ Okv,
    float* __restrict__ Osk) {
    const int wsel = blockIdx.y;
    const __bf16* W = (wsel == 0) ? Wq : (wsel == 1) ? Wk : (wsel == 2) ? Wv : Wsk;
    const float*  B = (wsel == 0) ? Bq : (wsel == 1) ? Bk : (wsel == 2) ? Bv : Bs;

    int t = threadIdx.x;
    int wave = t >> 6, l = t & 63;
    int lo5 = l & 31, hi = l >> 5;
    int row0 = blockIdx.x * 32;
    int col0 = wave * 32;

    const bf16x8* arow = (const bf16x8*)(Xb + (size_t)(row0 + lo5) * DIM + hi * 8);
    const bf16x8* brow = (const bf16x8*)(W  + (size_t)(col0 + lo5) * DIM + hi * 8);

    f32x16 acc = {};
#pragma unroll
    for (int kt = 0; kt < 8; ++kt)
        acc = __builtin_amdgcn_mfma_f32_32x32x16_bf16(arow[kt * 2], brow[kt * 2], acc, 0, 0, 0);

    float bias = B[col0 + lo5];
    if (wsel == 3) {
#pragma unroll
        for (int r = 0; r < 16; ++r) {
            int row = row0 + (r & 3) + 8 * (r >> 2) + 4 * hi;
            if (row < N_NODES)
                Osk[(size_t)row * DIM + col0 + lo5] = acc[r] + bias;
        }
    } else {
        __bf16* O; size_t stride; int coff;
        if (wsel == 0) { O = Oq;  stride = DIM;     coff = 0; }
        else           { O = Okv; stride = 2 * DIM; coff = (wsel == 2) ? DIM : 0; }
#pragma unroll
        for (int r = 0; r < 16; ++r) {
            int row = row0 + (r & 3) + 8 * (r >> 2) + 4 * hi;
            if (row < N_NODES)
                O[(size_t)row * stride + coff + col0 + lo5] = (__bf16)(acc[r] + bias);
        }
    }
}

// ---------------------------------------------------------------- fused alpha + softmax + aggregate (+skip+relu)
// One node per WAVE; 4x16-lane groups split the node's edges (group g takes
// e = start+g, +4, +8, ...), 2-edge unroll => 8 gathers in flight per wave.
// No-max softmax: w = exp(min(alpha,80)) -- no carried max, no rescale, merge = add.
__global__ __launch_bounds__(256) void k_edge_fused(const __bf16* __restrict__ q,
                                                    const __bf16* __restrict__ kv,
                                                    const float* __restrict__ skip,
                                                    const int* __restrict__ src_s,
                                                    const int* __restrict__ off,
                                                    float* __restrict__ xout,
                                                    __bf16* __restrict__ xb,
                                                    int wf32) {
    int t = threadIdx.x;
    int wave = t >> 6, l = t & 63;
    int n = blockIdx.x * 4 + wave;               // 50000 = 12500 * 4, no tail
    if (n >= N_NODES) return;
    int g = l >> 4, gl = l & 15;                 // 4 groups of 16 lanes
    int start = off[n], end = off[n + 1];

    // q fragment: 8 dims per lane (same row for all 4 groups)
    float qf[8];
    {
        bf16x8 qv = *(const bf16x8*)(q + (size_t)n * DIM + gl * 8);
#pragma unroll
        for (int j = 0; j < 8; ++j) qf[j] = (float)qv[j];
    }

    float denom = 0.f;
    float facc[8] = {};
    const float S = 0.08838834764831845f;        // 1/sqrt(128)

    for (int e = start + g; e < end; e += 8) {   // this group's edges, 2 per iter
        int s0 = src_s[e];
        bool h1 = (e + 4 < end);
        int s1 = h1 ? src_s[e + 4] : s0;         // dummy (w1 forced to 0)
        const bf16x8* r0 = (const bf16x8*)(kv + (size_t)s0 * (2 * DIM) + gl * 8);
        const bf16x8* r1 = (const bf16x8*)(kv + (size_t)s1 * (2 * DIM) + gl * 8);
        bf16x8 k0 = r0[0],  k1 = r1[0];
        bf16x8 v0 = r0[16], v1 = r1[16];         // v at +128 elems

        float p0 = 0.f, p1 = 0.f;
#pragma unroll
        for (int j = 0; j < 8; ++j) {
            p0 += qf[j] * (float)k0[j];
            p1 += qf[j] * (float)k1[j];
        }
        p0 += __shfl_xor(p0, 8, 16);  p1 += __shfl_xor(p1, 8, 16);
        p0 += __shfl_xor(p0, 4, 16);  p1 += __shfl_xor(p1, 4, 16);
        p0 += __shfl_xor(p0, 2, 16);  p1 += __shfl_xor(p1, 2, 16);
        p0 += __shfl_xor(p0, 1, 16);  p1 += __shfl_xor(p1, 1, 16);
        p0 = fminf(p0 * S, 80.f);                // overflow insurance only
        p1 = h1 ? fminf(p1 * S, 80.f) : -INFINITY;

        float w0 = __expf(p0);
        float w1 = __expf(p1);                   // exp(-inf) = 0 kills the tail slot
        denom += w0 + w1;
#pragma unroll
        for (int j = 0; j < 8; ++j)
            facc[j] += w0 * (float)v0[j] + w1 * (float)v1[j];
    }

    // merge the 4 groups: plain adds (no rescale needed without max-tracking)
#pragma unroll
    for (int dlt = 16; dlt <= 32; dlt <<= 1) {
        denom += __shfl_xor(denom, dlt, 64);
#pragma unroll
        for (int j = 0; j < 8; ++j) facc[j] += __shfl_xor(facc[j], dlt, 64);
    }
    float inv = (denom > 0.f) ? 1.f / denom : 0.f;

    if (g == 0) {
        const float* skrow = skip + (size_t)n * DIM + gl * 8;
        float4 s4a = *(const float4*)(skrow);
        float4 s4b = *(const float4*)(skrow + 4);
        float o[8] = { s4a.x, s4a.y, s4a.z, s4a.w, s4b.x, s4b.y, s4b.z, s4b.w };
        bf16x8 ob;
#pragma unroll
        for (int j = 0; j < 8; ++j) {
            float val = fmaxf(o[j] + facc[j] * inv, 0.f);
            o[j] = val; ob[j] = (__bf16)val;
        }
        if (wf32) {
            float* xrow = xout + (size_t)n * DIM + gl * 8;
            *(float4*)(xrow)     = make_float4(o[0], o[1], o[2], o[3]);
            *(float4*)(xrow + 4) = make_float4(o[4], o[5], o[6], o[7]);
        }
        *(bf16x8*)(xb + (size_t)n * DIM + gl * 8) = ob;
    }
}

// ---------------------------------------------------------------- mean pool
__global__ __launch_bounds__(256) void k_pool(const float* __restrict__ x,
                                              const int* __restrict__ batch,
                                              float* __restrict__ out) {
    __shared__ float sacc[4][DIM];
    int g = blockIdx.x;
    int t = threadIdx.x;
    int w = t >> 6, l = t & 63;
    int lo = 0, hi = N_NODES;
    while (lo < hi) { int mid = (lo + hi) >> 1; if (batch[mid] < g) lo = mid + 1; else hi = mid; }
    int s0 = lo;
    hi = N_NODES;
    while (lo < hi) { int mid = (lo + hi) >> 1; if (batch[mid] < g + 1) lo = mid + 1; else hi = mid; }
    int s1 = lo;
    float a0 = 0.f, a1 = 0.f;
    for (int n = s0 + w; n < s1; n += 4) {
        float2 xr = *(const float2*)(x + (size_t)n * DIM + l * 2);
        a0 += xr.x; a1 += xr.y;
    }
    sacc[w][l * 2] = a0; sacc[w][l * 2 + 1] = a1;
    __syncthreads();
    if (t < DIM) {
        float s = sacc[0][t] + sacc[1][t] + sacc[2][t] + sacc[3][t];
        int cnt = s1 - s0;
        out[(size_t)g * DIM + t] = s / (float)((cnt > 0) ? cnt : 1);
    }
}

// ----------------------------------------------------------------
extern "C" void kernel_launch(void* const* d_in, const int* in_sizes, int n_in,
                              void* d_out, int out_size, void* d_ws, size_t ws_size,
                              hipStream_t stream) {
    const float* x0   = (const float*)d_in[0];
    const int*  eidx  = (const int*)d_in[1];
    const int*  batch = (const int*)d_in[2];
    const float* Wq = (const float*)d_in[3];
    const float* bq = (const float*)d_in[4];
    const float* Wk = (const float*)d_in[5];
    const float* bk = (const float*)d_in[6];
    const float* Wv = (const float*)d_in[7];
    const float* bv = (const float*)d_in[8];
    const float* Ws = (const float*)d_in[9];
    const float* bs = (const float*)d_in[10];
    float* out = (float*)d_out;

    const int* src = eidx;
    const int* dst = eidx + N_EDGES;

    char* ws = (char*)d_ws;
    size_t p = 0;
    auto alloc = [&](size_t bytes) -> void* {
        void* r = ws + p;
        p = (p + bytes + 255) & ~(size_t)255;
        return r;
    };
    int*    off    = (int*)alloc((N_NODES + 1) * sizeof(int));
    int*    cnt    = (int*)alloc(N_NODES * sizeof(int));
    int*    bsum   = (int*)alloc(256 * sizeof(int));
    int*    boff   = (int*)alloc(256 * sizeof(int));
    int*    src_s  = (int*)alloc(N_EDGES * sizeof(int));
    __bf16* Xb     = (__bf16*)alloc((size_t)N_NODES * DIM * sizeof(__bf16));
    __bf16* qb     = (__bf16*)alloc((size_t)N_NODES * DIM * sizeof(__bf16));
    __bf16* kvb    = (__bf16*)alloc((size_t)N_NODES * 2 * DIM * sizeof(__bf16));
    float*  s1     = (float*)alloc((size_t)N_NODES * DIM * sizeof(float));
    __bf16* Wqb    = (__bf16*)alloc((size_t)NLAYERS * DIM * DIM * sizeof(__bf16));
    __bf16* Wkb    = (__bf16*)alloc((size_t)NLAYERS * DIM * DIM * sizeof(__bf16));
    __bf16* Wvb    = (__bf16*)alloc((size_t)NLAYERS * DIM * DIM * sizeof(__bf16));
    __bf16* Wsb    = (__bf16*)alloc((size_t)NLAYERS * DIM * DIM * sizeof(__bf16));

    // ---- casts
    {
        int nx = N_NODES * DIM;
        k_cast<<<(nx / 8 + 255) / 256, 256, 0, stream>>>(x0, Xb, nx);
        int nw = NLAYERS * DIM * DIM;
        dim3 gw((nw / 8 + 255) / 256, 4);
        k_cast4<<<gw, 256, 0, stream>>>(Wq, Wk, Wv, Ws, Wqb, Wkb, Wvb, Wsb, nw);
    }

    // ---- build CSR
    hipMemsetAsync(cnt, 0, N_NODES * sizeof(int), stream);
    k_degree<<<(N_EDGES + 255) / 256, 256, 0, stream>>>(dst, cnt);
    k_scan1<<<SCAN_NB, 256, 0, stream>>>(cnt, off, bsum);
    k_scan2<<<1, 256, 0, stream>>>(bsum, boff, off + N_NODES);
    k_scan3<<<SCAN_NB, 256, 0, stream>>>(off, boff);
    hipMemsetAsync(cnt, 0, N_NODES * sizeof(int), stream);
    k_scatter<<<(N_EDGES + 255) / 256, 256, 0, stream>>>(src, dst, off, cnt, src_s);

    // ---- layers
    for (int l = 0; l < NLAYERS; ++l) {
        const __bf16* wq = Wqb + (size_t)l * DIM * DIM;
        const __bf16* wk = Wkb + (size_t)l * DIM * DIM;
        const __bf16* wv = Wvb + (size_t)l * DIM * DIM;
        const __bf16* wsk = Wsb + (size_t)l * DIM * DIM;
        const float* biq = bq + (size_t)l * DIM;
        const float* bik = bk + (size_t)l * DIM;
        const float* biv = bv + (size_t)l * DIM;
        const float* bis = bs + (size_t)l * DIM;

        dim3 ggrid((N_NODES + 31) / 32, 4);
        k_gemm_mfma<<<ggrid, 256, 0, stream>>>(Xb, wq, wk, wv, wsk,
                                               biq, bik, biv, bis,
                                               qb, kvb, s1);
        int wf32 = (l == NLAYERS - 1) ? 1 : 0;
        k_edge_fused<<<(N_NODES + 3) / 4, 256, 0, stream>>>(qb, kvb, s1, src_s, off,
                                                            s1, Xb, wf32);
    }

    // ---- mean pool
    k_pool<<<NGRAPH, 256, 0, stream>>>(s1, batch, out);
}

// Round 9
// 418.142 us; speedup vs baseline: 1.1321x; 1.0780x over previous
//
#include <hip/hip_runtime.h>

#define N_NODES 50000
#define N_EDGES 800000
#define DIM 128
#define NLAYERS 3
#define NGRAPH 512
#define SCAN_NB ((N_NODES + 255) / 256)   // 196

typedef __attribute__((ext_vector_type(8)))  __bf16 bf16x8;
typedef __attribute__((ext_vector_type(16))) float  f32x16;

// ---------------------------------------------------------------- fp32 -> bf16 cast
__global__ __launch_bounds__(256) void k_cast(const float* __restrict__ in,
                                              __bf16* __restrict__ out, int n) {
    int i = blockIdx.x * blockDim.x + threadIdx.x;
    int base = i * 8;
    if (base >= n) return;
    float4 a = *(const float4*)(in + base);
    float4 b = *(const float4*)(in + base + 4);
    bf16x8 o;
    o[0] = (__bf16)a.x; o[1] = (__bf16)a.y; o[2] = (__bf16)a.z; o[3] = (__bf16)a.w;
    o[4] = (__bf16)b.x; o[5] = (__bf16)b.y; o[6] = (__bf16)b.z; o[7] = (__bf16)b.w;
    *(bf16x8*)(out + base) = o;
}

// 4 weight tensors in one launch (blockIdx.y selects)
__global__ __launch_bounds__(256) void k_cast4(
    const float* __restrict__ i0, const float* __restrict__ i1,
    const float* __restrict__ i2, const float* __restrict__ i3,
    __bf16* __restrict__ o0, __bf16* __restrict__ o1,
    __bf16* __restrict__ o2, __bf16* __restrict__ o3, int n) {
    int sel = blockIdx.y;
    const float* in = (sel == 0) ? i0 : (sel == 1) ? i1 : (sel == 2) ? i2 : i3;
    __bf16* out     = (sel == 0) ? o0 : (sel == 1) ? o1 : (sel == 2) ? o2 : o3;
    int i = blockIdx.x * blockDim.x + threadIdx.x;
    int base = i * 8;
    if (base >= n) return;
    float4 a = *(const float4*)(in + base);
    float4 b = *(const float4*)(in + base + 4);
    bf16x8 o;
    o[0] = (__bf16)a.x; o[1] = (__bf16)a.y; o[2] = (__bf16)a.z; o[3] = (__bf16)a.w;
    o[4] = (__bf16)b.x; o[5] = (__bf16)b.y; o[6] = (__bf16)b.z; o[7] = (__bf16)b.w;
    *(bf16x8*)(out + base) = o;
}

// ---------------------------------------------------------------- degree
__global__ __launch_bounds__(256) void k_degree(const int* __restrict__ dst,
                                                int* __restrict__ cnt) {
    int i = blockIdx.x * blockDim.x + threadIdx.x;
    if (i < N_EDGES) atomicAdd(&cnt[dst[i]], 1);
}

// ---------------------------------------------------------------- hierarchical scan
__global__ __launch_bounds__(256) void k_scan1(const int* __restrict__ cnt,
                                               int* __restrict__ off,
                                               int* __restrict__ bsum) {
    __shared__ int s[256];
    int b = blockIdx.x, t = threadIdx.x;
    int i = b * 256 + t;
    int v = (i < N_NODES) ? cnt[i] : 0;
    s[t] = v; __syncthreads();
#pragma unroll
    for (int d = 1; d < 256; d <<= 1) {
        int nv = (t >= d) ? s[t - d] : 0;
        __syncthreads();
        s[t] += nv;
        __syncthreads();
    }
    if (i < N_NODES) off[i] = s[t] - v;
    if (t == 255) bsum[b] = s[255];
}

__global__ __launch_bounds__(256) void k_scan2(const int* __restrict__ bsum,
                                               int* __restrict__ boff,
                                               int* __restrict__ offN) {
    __shared__ int s[256];
    int t = threadIdx.x;
    int v = (t < SCAN_NB) ? bsum[t] : 0;
    s[t] = v; __syncthreads();
#pragma unroll
    for (int d = 1; d < 256; d <<= 1) {
        int nv = (t >= d) ? s[t - d] : 0;
        __syncthreads();
        s[t] += nv;
        __syncthreads();
    }
    boff[t] = s[t] - v;
    if (t == 255) *offN = s[255];
}

__global__ __launch_bounds__(256) void k_scan3(int* __restrict__ off,
                                               const int* __restrict__ boff) {
    int b = blockIdx.x, t = threadIdx.x;
    int i = b * 256 + t;
    if (i < N_NODES) off[i] += boff[b];
}

// ---------------------------------------------------------------- scatter to CSR (src only)
__global__ __launch_bounds__(256) void k_scatter(const int* __restrict__ src,
                                                 const int* __restrict__ dst,
                                                 const int* __restrict__ off,
                                                 int* __restrict__ cursor,
                                                 int* __restrict__ src_s) {
    int i = blockIdx.x * blockDim.x + threadIdx.x;
    if (i < N_EDGES) {
        int d = dst[i];
        int pos = off[d] + atomicAdd(&cursor[d], 1);
        src_s[pos] = src[i];
    }
}

// ---------------------------------------------------------------- fused 4-matrix MFMA GEMM
// One block = 32 rows, 4 waves; wave w computes matrix w (q,k,v,skip) for all
// 128 cols. A-fragments identical across waves -> L1-shared; X read once.
__global__ __launch_bounds__(256) void k_gemm_fused(
    const __bf16* __restrict__ Xb,
    const __bf16* __restrict__ Wq, const __bf16* __restrict__ Wk,
    const __bf16* __restrict__ Wv, const __bf16* __restrict__ Wsk,
    const float* __restrict__ Bq, const float* __restrict__ Bk,
    const float* __restrict__ Bv, const float* __restrict__ Bs,
    __bf16* __restrict__ Oq, __bf16* __restrict__ Okv,
    float* __restrict__ Osk) {
    int t = threadIdx.x;
    int wsel = t >> 6, l = t & 63;
    int lo5 = l & 31, hi = l >> 5;
    int row0 = blockIdx.x * 32;

    const __bf16* W = (wsel == 0) ? Wq : (wsel == 1) ? Wk : (wsel == 2) ? Wv : Wsk;
    const float*  B = (wsel == 0) ? Bq : (wsel == 1) ? Bk : (wsel == 2) ? Bv : Bs;

    // A fragments for the 32-row tile: 8 x bf16x8 (lane: row row0+lo5, k = kt*16 + hi*8)
    const bf16x8* arow = (const bf16x8*)(Xb + (size_t)(row0 + lo5) * DIM + hi * 8);
    bf16x8 a[8];
#pragma unroll
    for (int kt = 0; kt < 8; ++kt) a[kt] = arow[kt * 2];

    // output target per matrix
    __bf16* O; size_t stride; int coff;
    if (wsel == 0)      { O = Oq;  stride = DIM;     coff = 0;   }
    else if (wsel == 1) { O = Okv; stride = 2 * DIM; coff = 0;   }
    else                { O = Okv; stride = 2 * DIM; coff = DIM; }  // wsel==2 (v); wsel==3 unused

#pragma unroll
    for (int ct = 0; ct < 4; ++ct) {
        int col0 = ct * 32;
        const bf16x8* brow = (const bf16x8*)(W + (size_t)(col0 + lo5) * DIM + hi * 8);
        f32x16 acc = {};
#pragma unroll
        for (int kt = 0; kt < 8; ++kt)
            acc = __builtin_amdgcn_mfma_f32_32x32x16_bf16(a[kt], brow[kt * 2], acc, 0, 0, 0);

        float bias = B[col0 + lo5];
        if (wsel == 3) {
#pragma unroll
            for (int r = 0; r < 16; ++r) {
                int row = row0 + (r & 3) + 8 * (r >> 2) + 4 * hi;
                if (row < N_NODES)
                    Osk[(size_t)row * DIM + col0 + lo5] = acc[r] + bias;
            }
        } else {
#pragma unroll
            for (int r = 0; r < 16; ++r) {
                int row = row0 + (r & 3) + 8 * (r >> 2) + 4 * hi;
                if (row < N_NODES)
                    O[(size_t)row * stride + coff + col0 + lo5] = (__bf16)(acc[r] + bias);
            }
        }
    }
}

// ---------------------------------------------------------------- fused alpha + softmax + aggregate (+skip+relu)
// One node per WAVE; 4x16-lane groups split the node's edges, 2-edge unroll.
// No-max softmax: w = exp(min(alpha,80)) -- merge = plain add.
__global__ __launch_bounds__(256) void k_edge_fused(const __bf16* __restrict__ q,
                                                    const __bf16* __restrict__ kv,
                                                    const float* __restrict__ skip,
                                                    const int* __restrict__ src_s,
                                                    const int* __restrict__ off,
                                                    float* __restrict__ xout,
                                                    __bf16* __restrict__ xb,
                                                    int wf32) {
    int t = threadIdx.x;
    int wave = t >> 6, l = t & 63;
    int n = blockIdx.x * 4 + wave;               // 50000 = 12500 * 4
    if (n >= N_NODES) return;
    int g = l >> 4, gl = l & 15;                 // 4 groups of 16 lanes
    int start = off[n], end = off[n + 1];

    float qf[8];
    {
        bf16x8 qv = *(const bf16x8*)(q + (size_t)n * DIM + gl * 8);
#pragma unroll
        for (int j = 0; j < 8; ++j) qf[j] = (float)qv[j];
    }

    float denom = 0.f;
    float facc[8] = {};
    const float S = 0.08838834764831845f;        // 1/sqrt(128)

    for (int e = start + g; e < end; e += 8) {
        int s0 = src_s[e];
        bool h1 = (e + 4 < end);
        int s1 = h1 ? src_s[e + 4] : s0;
        const bf16x8* r0 = (const bf16x8*)(kv + (size_t)s0 * (2 * DIM) + gl * 8);
        const bf16x8* r1 = (const bf16x8*)(kv + (size_t)s1 * (2 * DIM) + gl * 8);
        bf16x8 k0 = r0[0],  k1 = r1[0];
        bf16x8 v0 = r0[16], v1 = r1[16];

        float p0 = 0.f, p1 = 0.f;
#pragma unroll
        for (int j = 0; j < 8; ++j) {
            p0 += qf[j] * (float)k0[j];
            p1 += qf[j] * (float)k1[j];
        }
        p0 += __shfl_xor(p0, 8, 16);  p1 += __shfl_xor(p1, 8, 16);
        p0 += __shfl_xor(p0, 4, 16);  p1 += __shfl_xor(p1, 4, 16);
        p0 += __shfl_xor(p0, 2, 16);  p1 += __shfl_xor(p1, 2, 16);
        p0 += __shfl_xor(p0, 1, 16);  p1 += __shfl_xor(p1, 1, 16);
        p0 = fminf(p0 * S, 80.f);
        p1 = h1 ? fminf(p1 * S, 80.f) : -INFINITY;

        float w0 = __expf(p0);
        float w1 = __expf(p1);
        denom += w0 + w1;
#pragma unroll
        for (int j = 0; j < 8; ++j)
            facc[j] += w0 * (float)v0[j] + w1 * (float)v1[j];
    }

#pragma unroll
    for (int dlt = 16; dlt <= 32; dlt <<= 1) {
        denom += __shfl_xor(denom, dlt, 64);
#pragma unroll
        for (int j = 0; j < 8; ++j) facc[j] += __shfl_xor(facc[j], dlt, 64);
    }
    float inv = (denom > 0.f) ? 1.f / denom : 0.f;

    if (g == 0) {
        const float* skrow = skip + (size_t)n * DIM + gl * 8;
        float4 s4a = *(const float4*)(skrow);
        float4 s4b = *(const float4*)(skrow + 4);
        float o[8] = { s4a.x, s4a.y, s4a.z, s4a.w, s4b.x, s4b.y, s4b.z, s4b.w };
        bf16x8 ob;
#pragma unroll
        for (int j = 0; j < 8; ++j) {
            float val = fmaxf(o[j] + facc[j] * inv, 0.f);
            o[j] = val; ob[j] = (__bf16)val;
        }
        if (wf32) {
            float* xrow = xout + (size_t)n * DIM + gl * 8;
            *(float4*)(xrow)     = make_float4(o[0], o[1], o[2], o[3]);
            *(float4*)(xrow + 4) = make_float4(o[4], o[5], o[6], o[7]);
        }
        *(bf16x8*)(xb + (size_t)n * DIM + gl * 8) = ob;
    }
}

// ---------------------------------------------------------------- mean pool
__global__ __launch_bounds__(256) void k_pool(const float* __restrict__ x,
                                              const int* __restrict__ batch,
                                              float* __restrict__ out) {
    __shared__ float sacc[4][DIM];
    int g = blockIdx.x;
    int t = threadIdx.x;
    int w = t >> 6, l = t & 63;
    int lo = 0, hi = N_NODES;
    while (lo < hi) { int mid = (lo + hi) >> 1; if (batch[mid] < g) lo = mid + 1; else hi = mid; }
    int s0 = lo;
    hi = N_NODES;
    while (lo < hi) { int mid = (lo + hi) >> 1; if (batch[mid] < g + 1) lo = mid + 1; else hi = mid; }
    int s1 = lo;
    float a0 = 0.f, a1 = 0.f;
    for (int n = s0 + w; n < s1; n += 4) {
        float2 xr = *(const float2*)(x + (size_t)n * DIM + l * 2);
        a0 += xr.x; a1 += xr.y;
    }
    sacc[w][l * 2] = a0; sacc[w][l * 2 + 1] = a1;
    __syncthreads();
    if (t < DIM) {
        float s = sacc[0][t] + sacc[1][t] + sacc[2][t] + sacc[3][t];
        int cnt = s1 - s0;
        out[(size_t)g * DIM + t] = s / (float)((cnt > 0) ? cnt : 1);
    }
}

// ----------------------------------------------------------------
extern "C" void kernel_launch(void* const* d_in, const int* in_sizes, int n_in,
                              void* d_out, int out_size, void* d_ws, size_t ws_size,
                              hipStream_t stream) {
    const float* x0   = (const float*)d_in[0];
    const int*  eidx  = (const int*)d_in[1];
    const int*  batch = (const int*)d_in[2];
    const float* Wq = (const float*)d_in[3];
    const float* bq = (const float*)d_in[4];
    const float* Wk = (const float*)d_in[5];
    const float* bk = (const float*)d_in[6];
    const float* Wv = (const float*)d_in[7];
    const float* bv = (const float*)d_in[8];
    const float* Ws = (const float*)d_in[9];
    const float* bs = (const float*)d_in[10];
    float* out = (float*)d_out;

    const int* src = eidx;
    const int* dst = eidx + N_EDGES;

    char* ws = (char*)d_ws;
    size_t p = 0;
    auto alloc = [&](size_t bytes) -> void* {
        void* r = ws + p;
        p = (p + bytes + 255) & ~(size_t)255;
        return r;
    };
    int*    off    = (int*)alloc((N_NODES + 1) * sizeof(int));
    int*    cnt    = (int*)alloc(N_NODES * sizeof(int));
    int*    bsum   = (int*)alloc(256 * sizeof(int));
    int*    boff   = (int*)alloc(256 * sizeof(int));
    int*    src_s  = (int*)alloc(N_EDGES * sizeof(int));
    __bf16* Xb     = (__bf16*)alloc((size_t)N_NODES * DIM * sizeof(__bf16));
    __bf16* qb     = (__bf16*)alloc((size_t)N_NODES * DIM * sizeof(__bf16));
    __bf16* kvb    = (__bf16*)alloc((size_t)N_NODES * 2 * DIM * sizeof(__bf16));
    float*  s1     = (float*)alloc((size_t)N_NODES * DIM * sizeof(float));
    __bf16* Wqb    = (__bf16*)alloc((size_t)NLAYERS * DIM * DIM * sizeof(__bf16));
    __bf16* Wkb    = (__bf16*)alloc((size_t)NLAYERS * DIM * DIM * sizeof(__bf16));
    __bf16* Wvb    = (__bf16*)alloc((size_t)NLAYERS * DIM * DIM * sizeof(__bf16));
    __bf16* Wsb    = (__bf16*)alloc((size_t)NLAYERS * DIM * DIM * sizeof(__bf16));

    // ---- casts
    {
        int nx = N_NODES * DIM;
        k_cast<<<(nx / 8 + 255) / 256, 256, 0, stream>>>(x0, Xb, nx);
        int nw = NLAYERS * DIM * DIM;
        dim3 gw((nw / 8 + 255) / 256, 4);
        k_cast4<<<gw, 256, 0, stream>>>(Wq, Wk, Wv, Ws, Wqb, Wkb, Wvb, Wsb, nw);
    }

    // ---- build CSR
    hipMemsetAsync(cnt, 0, N_NODES * sizeof(int), stream);
    k_degree<<<(N_EDGES + 255) / 256, 256, 0, stream>>>(dst, cnt);
    k_scan1<<<SCAN_NB, 256, 0, stream>>>(cnt, off, bsum);
    k_scan2<<<1, 256, 0, stream>>>(bsum, boff, off + N_NODES);
    k_scan3<<<SCAN_NB, 256, 0, stream>>>(off, boff);
    hipMemsetAsync(cnt, 0, N_NODES * sizeof(int), stream);
    k_scatter<<<(N_EDGES + 255) / 256, 256, 0, stream>>>(src, dst, off, cnt, src_s);

    // ---- layers
    for (int l = 0; l < NLAYERS; ++l) {
        const __bf16* wq = Wqb + (size_t)l * DIM * DIM;
        const __bf16* wk = Wkb + (size_t)l * DIM * DIM;
        const __bf16* wv = Wvb + (size_t)l * DIM * DIM;
        const __bf16* wsk = Wsb + (size_t)l * DIM * DIM;
        const float* biq = bq + (size_t)l * DIM;
        const float* bik = bk + (size_t)l * DIM;
        const float* biv = bv + (size_t)l * DIM;
        const float* bis = bs + (size_t)l * DIM;

        k_gemm_fused<<<(N_NODES + 31) / 32, 256, 0, stream>>>(Xb, wq, wk, wv, wsk,
                                                              biq, bik, biv, bis,
                                                              qb, kvb, s1);
        int wf32 = (l == NLAYERS - 1) ? 1 : 0;
        k_edge_fused<<<(N_NODES + 3) / 4, 256, 0, stream>>>(qb, kvb, s1, src_s, off,
                                                            s1, Xb, wf32);
    }

    // ---- mean pool
    k_pool<<<NGRAPH, 256, 0, stream>>>(s1, batch, out);
}

// Round 10
// 379.028 us; speedup vs baseline: 1.2489x; 1.1032x over previous
//
#include <hip/hip_runtime.h>
#include <hip/hip_fp8.h>

#define N_NODES 50000
#define N_EDGES 800000
#define DIM 128
#define NLAYERS 3
#define NGRAPH 512
#define SCAN_NB ((N_NODES + 255) / 256)   // 196

typedef __attribute__((ext_vector_type(8)))  __bf16 bf16x8;
typedef __attribute__((ext_vector_type(16))) float  f32x16;

union U8 { uint2 u; unsigned char b[8]; };

__device__ inline void cvt8_fp8_f32(U8 x, float* f) {
#pragma unroll
    for (int j = 0; j < 8; ++j) {
        __hip_fp8_e4m3 t; t.__x = x.b[j];
        f[j] = (float)t;
    }
}

// ---------------------------------------------------------------- fp32 -> bf16 cast
__global__ __launch_bounds__(256) void k_cast(const float* __restrict__ in,
                                              __bf16* __restrict__ out, int n) {
    int i = blockIdx.x * blockDim.x + threadIdx.x;
    int base = i * 8;
    if (base >= n) return;
    float4 a = *(const float4*)(in + base);
    float4 b = *(const float4*)(in + base + 4);
    bf16x8 o;
    o[0] = (__bf16)a.x; o[1] = (__bf16)a.y; o[2] = (__bf16)a.z; o[3] = (__bf16)a.w;
    o[4] = (__bf16)b.x; o[5] = (__bf16)b.y; o[6] = (__bf16)b.z; o[7] = (__bf16)b.w;
    *(bf16x8*)(out + base) = o;
}

// 4 weight tensors in one launch (blockIdx.y selects)
__global__ __launch_bounds__(256) void k_cast4(
    const float* __restrict__ i0, const float* __restrict__ i1,
    const float* __restrict__ i2, const float* __restrict__ i3,
    __bf16* __restrict__ o0, __bf16* __restrict__ o1,
    __bf16* __restrict__ o2, __bf16* __restrict__ o3, int n) {
    int sel = blockIdx.y;
    const float* in = (sel == 0) ? i0 : (sel == 1) ? i1 : (sel == 2) ? i2 : i3;
    __bf16* out     = (sel == 0) ? o0 : (sel == 1) ? o1 : (sel == 2) ? o2 : o3;
    int i = blockIdx.x * blockDim.x + threadIdx.x;
    int base = i * 8;
    if (base >= n) return;
    float4 a = *(const float4*)(in + base);
    float4 b = *(const float4*)(in + base + 4);
    bf16x8 o;
    o[0] = (__bf16)a.x; o[1] = (__bf16)a.y; o[2] = (__bf16)a.z; o[3] = (__bf16)a.w;
    o[4] = (__bf16)b.x; o[5] = (__bf16)b.y; o[6] = (__bf16)b.z; o[7] = (__bf16)b.w;
    *(bf16x8*)(out + base) = o;
}

// ---------------------------------------------------------------- degree
__global__ __launch_bounds__(256) void k_degree(const int* __restrict__ dst,
                                                int* __restrict__ cnt) {
    int i = blockIdx.x * blockDim.x + threadIdx.x;
    if (i < N_EDGES) atomicAdd(&cnt[dst[i]], 1);
}

// ---------------------------------------------------------------- hierarchical scan
__global__ __launch_bounds__(256) void k_scan1(const int* __restrict__ cnt,
                                               int* __restrict__ off,
                                               int* __restrict__ bsum) {
    __shared__ int s[256];
    int b = blockIdx.x, t = threadIdx.x;
    int i = b * 256 + t;
    int v = (i < N_NODES) ? cnt[i] : 0;
    s[t] = v; __syncthreads();
#pragma unroll
    for (int d = 1; d < 256; d <<= 1) {
        int nv = (t >= d) ? s[t - d] : 0;
        __syncthreads();
        s[t] += nv;
        __syncthreads();
    }
    if (i < N_NODES) off[i] = s[t] - v;
    if (t == 255) bsum[b] = s[255];
}

__global__ __launch_bounds__(256) void k_scan2(const int* __restrict__ bsum,
                                               int* __restrict__ boff,
                                               int* __restrict__ offN) {
    __shared__ int s[256];
    int t = threadIdx.x;
    int v = (t < SCAN_NB) ? bsum[t] : 0;
    s[t] = v; __syncthreads();
#pragma unroll
    for (int d = 1; d < 256; d <<= 1) {
        int nv = (t >= d) ? s[t - d] : 0;
        __syncthreads();
        s[t] += nv;
        __syncthreads();
    }
    boff[t] = s[t] - v;
    if (t == 255) *offN = s[255];
}

__global__ __launch_bounds__(256) void k_scan3(int* __restrict__ off,
                                               const int* __restrict__ boff) {
    int b = blockIdx.x, t = threadIdx.x;
    int i = b * 256 + t;
    if (i < N_NODES) off[i] += boff[b];
}

// ---------------------------------------------------------------- scatter to CSR (src only)
__global__ __launch_bounds__(256) void k_scatter(const int* __restrict__ src,
                                                 const int* __restrict__ dst,
                                                 const int* __restrict__ off,
                                                 int* __restrict__ cursor,
                                                 int* __restrict__ src_s) {
    int i = blockIdx.x * blockDim.x + threadIdx.x;
    if (i < N_EDGES) {
        int d = dst[i];
        int pos = off[d] + atomicAdd(&cursor[d], 1);
        src_s[pos] = src[i];
    }
}

// ---------------------------------------------------------------- fused 4-matrix MFMA GEMM
// One block = 32 rows, 4 waves; wave w computes matrix w (q,k,v,skip) for all
// 128 cols. q -> bf16 [node][128]; k,v -> fp8 e4m3 interleaved [node][k128B|v128B];
// skip -> fp32.
__global__ __launch_bounds__(256) void k_gemm_fused(
    const __bf16* __restrict__ Xb,
    const __bf16* __restrict__ Wq, const __bf16* __restrict__ Wk,
    const __bf16* __restrict__ Wv, const __bf16* __restrict__ Wsk,
    const float* __restrict__ Bq, const float* __restrict__ Bk,
    const float* __restrict__ Bv, const float* __restrict__ Bs,
    __bf16* __restrict__ Oq, unsigned char* __restrict__ Okv,
    float* __restrict__ Osk) {
    int t = threadIdx.x;
    int wsel = t >> 6, l = t & 63;
    int lo5 = l & 31, hi = l >> 5;
    int row0 = blockIdx.x * 32;

    const __bf16* W = (wsel == 0) ? Wq : (wsel == 1) ? Wk : (wsel == 2) ? Wv : Wsk;
    const float*  B = (wsel == 0) ? Bq : (wsel == 1) ? Bk : (wsel == 2) ? Bv : Bs;

    const bf16x8* arow = (const bf16x8*)(Xb + (size_t)(row0 + lo5) * DIM + hi * 8);
    bf16x8 a[8];
#pragma unroll
    for (int kt = 0; kt < 8; ++kt) a[kt] = arow[kt * 2];

#pragma unroll
    for (int ct = 0; ct < 4; ++ct) {
        int col0 = ct * 32;
        const bf16x8* brow = (const bf16x8*)(W + (size_t)(col0 + lo5) * DIM + hi * 8);
        f32x16 acc = {};
#pragma unroll
        for (int kt = 0; kt < 8; ++kt)
            acc = __builtin_amdgcn_mfma_f32_32x32x16_bf16(a[kt], brow[kt * 2], acc, 0, 0, 0);

        float bias = B[col0 + lo5];
        if (wsel == 3) {
#pragma unroll
            for (int r = 0; r < 16; ++r) {
                int row = row0 + (r & 3) + 8 * (r >> 2) + 4 * hi;
                if (row < N_NODES)
                    Osk[(size_t)row * DIM + col0 + lo5] = acc[r] + bias;
            }
        } else if (wsel == 0) {
#pragma unroll
            for (int r = 0; r < 16; ++r) {
                int row = row0 + (r & 3) + 8 * (r >> 2) + 4 * hi;
                if (row < N_NODES)
                    Oq[(size_t)row * DIM + col0 + lo5] = (__bf16)(acc[r] + bias);
            }
        } else {
            int coff = (wsel == 2) ? 128 : 0;   // k at +0, v at +128 bytes
#pragma unroll
            for (int r = 0; r < 16; ++r) {
                int row = row0 + (r & 3) + 8 * (r >> 2) + 4 * hi;
                if (row < N_NODES) {
                    __hip_fp8_e4m3 t8((float)(acc[r] + bias));
                    Okv[(size_t)row * 256 + coff + col0 + lo5] = t8.__x;
                }
            }
        }
    }
}

// ---------------------------------------------------------------- fused alpha + softmax + aggregate (+skip+relu)
// One node per WAVE; 4x16-lane groups split the node's edges, 2-edge unroll.
// k,v gathered as fp8 e4m3 (128B + 128B per node). No-max softmax.
__global__ __launch_bounds__(256) void k_edge_fused(const __bf16* __restrict__ q,
                                                    const unsigned char* __restrict__ kv,
                                                    const float* __restrict__ skip,
                                                    const int* __restrict__ src_s,
                                                    const int* __restrict__ off,
                                                    float* __restrict__ xout,
                                                    __bf16* __restrict__ xb,
                                                    int wf32) {
    int t = threadIdx.x;
    int wave = t >> 6, l = t & 63;
    int n = blockIdx.x * 4 + wave;               // 50000 = 12500 * 4
    if (n >= N_NODES) return;
    int g = l >> 4, gl = l & 15;                 // 4 groups of 16 lanes
    int start = off[n], end = off[n + 1];

    const float S = 0.08838834764831845f;        // 1/sqrt(128), folded into q
    float qf[8];
    {
        bf16x8 qv = *(const bf16x8*)(q + (size_t)n * DIM + gl * 8);
#pragma unroll
        for (int j = 0; j < 8; ++j) qf[j] = (float)qv[j] * S;
    }

    float denom = 0.f;
    float facc[8] = {};

    for (int e = start + g; e < end; e += 8) {   // this group's edges, 2 per iter
        int s0 = src_s[e];
        bool h1 = (e + 4 < end);
        int s1 = h1 ? src_s[e + 4] : s0;         // dummy (w1 forced to 0)
        const unsigned char* r0 = kv + (size_t)s0 * 256 + gl * 8;
        const unsigned char* r1 = kv + (size_t)s1 * 256 + gl * 8;
        U8 k0u, k1u, v0u, v1u;
        k0u.u = *(const uint2*)(r0);
        k1u.u = *(const uint2*)(r1);
        v0u.u = *(const uint2*)(r0 + 128);
        v1u.u = *(const uint2*)(r1 + 128);

        float k0f[8], k1f[8];
        cvt8_fp8_f32(k0u, k0f);
        cvt8_fp8_f32(k1u, k1f);
        float p0 = 0.f, p1 = 0.f;
#pragma unroll
        for (int j = 0; j < 8; ++j) {
            p0 += qf[j] * k0f[j];
            p1 += qf[j] * k1f[j];
        }
        p0 += __shfl_xor(p0, 8, 16);  p1 += __shfl_xor(p1, 8, 16);
        p0 += __shfl_xor(p0, 4, 16);  p1 += __shfl_xor(p1, 4, 16);
        p0 += __shfl_xor(p0, 2, 16);  p1 += __shfl_xor(p1, 2, 16);
        p0 += __shfl_xor(p0, 1, 16);  p1 += __shfl_xor(p1, 1, 16);
        p0 = fminf(p0, 80.f);                    // overflow insurance only
        p1 = h1 ? fminf(p1, 80.f) : -INFINITY;

        float w0 = __expf(p0);
        float w1 = __expf(p1);                   // exp(-inf) = 0 kills the tail slot
        denom += w0 + w1;

        float v0f[8], v1f[8];
        cvt8_fp8_f32(v0u, v0f);
        cvt8_fp8_f32(v1u, v1f);
#pragma unroll
        for (int j = 0; j < 8; ++j)
            facc[j] += w0 * v0f[j] + w1 * v1f[j];
    }

    // merge the 4 groups: plain adds
#pragma unroll
    for (int dlt = 16; dlt <= 32; dlt <<= 1) {
        denom += __shfl_xor(denom, dlt, 64);
#pragma unroll
        for (int j = 0; j < 8; ++j) facc[j] += __shfl_xor(facc[j], dlt, 64);
    }
    float inv = (denom > 0.f) ? 1.f / denom : 0.f;

    if (g == 0) {
        const float* skrow = skip + (size_t)n * DIM + gl * 8;
        float4 s4a = *(const float4*)(skrow);
        float4 s4b = *(const float4*)(skrow + 4);
        float o[8] = { s4a.x, s4a.y, s4a.z, s4a.w, s4b.x, s4b.y, s4b.z, s4b.w };
        bf16x8 ob;
#pragma unroll
        for (int j = 0; j < 8; ++j) {
            float val = fmaxf(o[j] + facc[j] * inv, 0.f);
            o[j] = val; ob[j] = (__bf16)val;
        }
        if (wf32) {
            float* xrow = xout + (size_t)n * DIM + gl * 8;
            *(float4*)(xrow)     = make_float4(o[0], o[1], o[2], o[3]);
            *(float4*)(xrow + 4) = make_float4(o[4], o[5], o[6], o[7]);
        }
        *(bf16x8*)(xb + (size_t)n * DIM + gl * 8) = ob;
    }
}

// ---------------------------------------------------------------- mean pool
__global__ __launch_bounds__(256) void k_pool(const float* __restrict__ x,
                                              const int* __restrict__ batch,
                                              float* __restrict__ out) {
    __shared__ float sacc[4][DIM];
    int g = blockIdx.x;
    int t = threadIdx.x;
    int w = t >> 6, l = t & 63;
    int lo = 0, hi = N_NODES;
    while (lo < hi) { int mid = (lo + hi) >> 1; if (batch[mid] < g) lo = mid + 1; else hi = mid; }
    int s0 = lo;
    hi = N_NODES;
    while (lo < hi) { int mid = (lo + hi) >> 1; if (batch[mid] < g + 1) lo = mid + 1; else hi = mid; }
    int s1 = lo;
    float a0 = 0.f, a1 = 0.f;
    for (int n = s0 + w; n < s1; n += 4) {
        float2 xr = *(const float2*)(x + (size_t)n * DIM + l * 2);
        a0 += xr.x; a1 += xr.y;
    }
    sacc[w][l * 2] = a0; sacc[w][l * 2 + 1] = a1;
    __syncthreads();
    if (t < DIM) {
        float s = sacc[0][t] + sacc[1][t] + sacc[2][t] + sacc[3][t];
        int cnt = s1 - s0;
        out[(size_t)g * DIM + t] = s / (float)((cnt > 0) ? cnt : 1);
    }
}

// ----------------------------------------------------------------
extern "C" void kernel_launch(void* const* d_in, const int* in_sizes, int n_in,
                              void* d_out, int out_size, void* d_ws, size_t ws_size,
                              hipStream_t stream) {
    const float* x0   = (const float*)d_in[0];
    const int*  eidx  = (const int*)d_in[1];
    const int*  batch = (const int*)d_in[2];
    const float* Wq = (const float*)d_in[3];
    const float* bq = (const float*)d_in[4];
    const float* Wk = (const float*)d_in[5];
    const float* bk = (const float*)d_in[6];
    const float* Wv = (const float*)d_in[7];
    const float* bv = (const float*)d_in[8];
    const float* Ws = (const float*)d_in[9];
    const float* bs = (const float*)d_in[10];
    float* out = (float*)d_out;

    const int* src = eidx;
    const int* dst = eidx + N_EDGES;

    char* ws = (char*)d_ws;
    size_t p = 0;
    auto alloc = [&](size_t bytes) -> void* {
        void* r = ws + p;
        p = (p + bytes + 255) & ~(size_t)255;
        return r;
    };
    int*    off    = (int*)alloc((N_NODES + 1) * sizeof(int));
    int*    cnt    = (int*)alloc(N_NODES * sizeof(int));
    int*    bsum   = (int*)alloc(256 * sizeof(int));
    int*    boff   = (int*)alloc(256 * sizeof(int));
    int*    src_s  = (int*)alloc(N_EDGES * sizeof(int));
    __bf16* Xb     = (__bf16*)alloc((size_t)N_NODES * DIM * sizeof(__bf16));
    __bf16* qb     = (__bf16*)alloc((size_t)N_NODES * DIM * sizeof(__bf16));
    unsigned char* kvb = (unsigned char*)alloc((size_t)N_NODES * 256);
    float*  s1     = (float*)alloc((size_t)N_NODES * DIM * sizeof(float));
    __bf16* Wqb    = (__bf16*)alloc((size_t)NLAYERS * DIM * DIM * sizeof(__bf16));
    __bf16* Wkb    = (__bf16*)alloc((size_t)NLAYERS * DIM * DIM * sizeof(__bf16));
    __bf16* Wvb    = (__bf16*)alloc((size_t)NLAYERS * DIM * DIM * sizeof(__bf16));
    __bf16* Wsb    = (__bf16*)alloc((size_t)NLAYERS * DIM * DIM * sizeof(__bf16));

    // ---- casts
    {
        int nx = N_NODES * DIM;
        k_cast<<<(nx / 8 + 255) / 256, 256, 0, stream>>>(x0, Xb, nx);
        int nw = NLAYERS * DIM * DIM;
        dim3 gw((nw / 8 + 255) / 256, 4);
        k_cast4<<<gw, 256, 0, stream>>>(Wq, Wk, Wv, Ws, Wqb, Wkb, Wvb, Wsb, nw);
    }

    // ---- build CSR
    hipMemsetAsync(cnt, 0, N_NODES * sizeof(int), stream);
    k_degree<<<(N_EDGES + 255) / 256, 256, 0, stream>>>(dst, cnt);
    k_scan1<<<SCAN_NB, 256, 0, stream>>>(cnt, off, bsum);
    k_scan2<<<1, 256, 0, stream>>>(bsum, boff, off + N_NODES);
    k_scan3<<<SCAN_NB, 256, 0, stream>>>(off, boff);
    hipMemsetAsync(cnt, 0, N_NODES * sizeof(int), stream);
    k_scatter<<<(N_EDGES + 255) / 256, 256, 0, stream>>>(src, dst, off, cnt, src_s);

    // ---- layers
    for (int l = 0; l < NLAYERS; ++l) {
        const __bf16* wq = Wqb + (size_t)l * DIM * DIM;
        const __bf16* wk = Wkb + (size_t)l * DIM * DIM;
        const __bf16* wv = Wvb + (size_t)l * DIM * DIM;
        const __bf16* wsk = Wsb + (size_t)l * DIM * DIM;
        const float* biq = bq + (size_t)l * DIM;
        const float* bik = bk + (size_t)l * DIM;
        const float* biv = bv + (size_t)l * DIM;
        const float* bis = bs + (size_t)l * DIM;

        k_gemm_fused<<<(N_NODES + 31) / 32, 256, 0, stream>>>(Xb, wq, wk, wv, wsk,
                                                              biq, bik, biv, bis,
                                                              qb, kvb, s1);
        int wf32 = (l == NLAYERS - 1) ? 1 : 0;
        k_edge_fused<<<(N_NODES + 3) / 4, 256, 0, stream>>>(qb, kvb, s1, src_s, off,
                                                            s1, Xb, wf32);
    }

    // ---- mean pool
    k_pool<<<NGRAPH, 256, 0, stream>>>(s1, batch, out);
}

// Round 11
// 357.023 us; speedup vs baseline: 1.3259x; 1.0616x over previous
//
#include <hip/hip_runtime.h>
#include <hip/hip_fp8.h>

#define N_NODES 50000
#define N_EDGES 800000
#define DIM 128
#define NLAYERS 3
#define NGRAPH 512
#define SCAN_NB ((N_NODES + 255) / 256)   // 196
#define NBUCK   ((N_NODES + 255) / 256)   // 196 buckets of 256 nodes (dst>>8)
#define P1_CHUNK 2048
#define P1_EPT   8                         // 2048 / 256
#define P1_NB    ((N_EDGES + P1_CHUNK - 1) / P1_CHUNK)   // 391

typedef __attribute__((ext_vector_type(8)))  __bf16 bf16x8;
typedef __attribute__((ext_vector_type(16))) float  f32x16;

union U8 { uint2 u; unsigned char b[8]; };

__device__ inline void cvt8_fp8_f32(U8 x, float* f) {
#pragma unroll
    for (int j = 0; j < 8; ++j) {
        __hip_fp8_e4m3 t; t.__x = x.b[j];
        f[j] = (float)t;
    }
}

// ---------------------------------------------------------------- fp32 -> bf16 cast
__global__ __launch_bounds__(256) void k_cast(const float* __restrict__ in,
                                              __bf16* __restrict__ out, int n) {
    int i = blockIdx.x * blockDim.x + threadIdx.x;
    int base = i * 8;
    if (base >= n) return;
    float4 a = *(const float4*)(in + base);
    float4 b = *(const float4*)(in + base + 4);
    bf16x8 o;
    o[0] = (__bf16)a.x; o[1] = (__bf16)a.y; o[2] = (__bf16)a.z; o[3] = (__bf16)a.w;
    o[4] = (__bf16)b.x; o[5] = (__bf16)b.y; o[6] = (__bf16)b.z; o[7] = (__bf16)b.w;
    *(bf16x8*)(out + base) = o;
}

// 4 weight tensors in one launch (blockIdx.y selects)
__global__ __launch_bounds__(256) void k_cast4(
    const float* __restrict__ i0, const float* __restrict__ i1,
    const float* __restrict__ i2, const float* __restrict__ i3,
    __bf16* __restrict__ o0, __bf16* __restrict__ o1,
    __bf16* __restrict__ o2, __bf16* __restrict__ o3, int n) {
    int sel = blockIdx.y;
    const float* in = (sel == 0) ? i0 : (sel == 1) ? i1 : (sel == 2) ? i2 : i3;
    __bf16* out     = (sel == 0) ? o0 : (sel == 1) ? o1 : (sel == 2) ? o2 : o3;
    int i = blockIdx.x * blockDim.x + threadIdx.x;
    int base = i * 8;
    if (base >= n) return;
    float4 a = *(const float4*)(in + base);
    float4 b = *(const float4*)(in + base + 4);
    bf16x8 o;
    o[0] = (__bf16)a.x; o[1] = (__bf16)a.y; o[2] = (__bf16)a.z; o[3] = (__bf16)a.w;
    o[4] = (__bf16)b.x; o[5] = (__bf16)b.y; o[6] = (__bf16)b.z; o[7] = (__bf16)b.w;
    *(bf16x8*)(out + base) = o;
}

// ---------------------------------------------------------------- degree
__global__ __launch_bounds__(256) void k_degree(const int* __restrict__ dst,
                                                int* __restrict__ cnt) {
    int i = blockIdx.x * blockDim.x + threadIdx.x;
    if (i < N_EDGES) atomicAdd(&cnt[dst[i]], 1);
}

// ---------------------------------------------------------------- hierarchical scan
__global__ __launch_bounds__(256) void k_scan1(const int* __restrict__ cnt,
                                               int* __restrict__ off,
                                               int* __restrict__ bsum) {
    __shared__ int s[256];
    int b = blockIdx.x, t = threadIdx.x;
    int i = b * 256 + t;
    int v = (i < N_NODES) ? cnt[i] : 0;
    s[t] = v; __syncthreads();
#pragma unroll
    for (int d = 1; d < 256; d <<= 1) {
        int nv = (t >= d) ? s[t - d] : 0;
        __syncthreads();
        s[t] += nv;
        __syncthreads();
    }
    if (i < N_NODES) off[i] = s[t] - v;
    if (t == 255) bsum[b] = s[255];
}

__global__ __launch_bounds__(256) void k_scan2(const int* __restrict__ bsum,
                                               int* __restrict__ boff,
                                               int* __restrict__ offN) {
    __shared__ int s[256];
    int t = threadIdx.x;
    int v = (t < SCAN_NB) ? bsum[t] : 0;
    s[t] = v; __syncthreads();
#pragma unroll
    for (int d = 1; d < 256; d <<= 1) {
        int nv = (t >= d) ? s[t - d] : 0;
        __syncthreads();
        s[t] += nv;
        __syncthreads();
    }
    boff[t] = s[t] - v;
    if (t == 255) *offN = s[255];
}

__global__ __launch_bounds__(256) void k_scan3(int* __restrict__ off,
                                               const int* __restrict__ boff) {
    int b = blockIdx.x, t = threadIdx.x;
    int i = b * 256 + t;
    if (i < N_NODES) off[i] += boff[b];
}

// ---------------------------------------------------------------- gcursor init (bucket bases)
__global__ __launch_bounds__(256) void k_ginit(const int* __restrict__ off,
                                               int* __restrict__ gcursor) {
    int t = threadIdx.x;
    if (t < NBUCK) gcursor[t] = off[t * 256];
}

// ---------------------------------------------------------------- pass 1: LDS-staged bucket binning
// Each block bins P1_CHUNK edges into NBUCK buckets (dst>>8) in LDS, reserves
// global bucket space with one atomicAdd per bucket, copies segments out densely.
__global__ __launch_bounds__(256) void k_bucket(const int* __restrict__ src,
                                                const int* __restrict__ dst,
                                                int* __restrict__ gcursor,
                                                unsigned long long* __restrict__ pairs) {
    __shared__ int lcount[256];
    __shared__ int lstart[256];
    __shared__ int lresv[256];
    __shared__ unsigned long long stage[P1_CHUNK];   // 16 KB
    int t = threadIdx.x;
    int base = blockIdx.x * P1_CHUNK;
    int cnt = N_EDGES - base; if (cnt > P1_CHUNK) cnt = P1_CHUNK;

    lcount[t] = 0;
    __syncthreads();

    int my_s[P1_EPT], my_d[P1_EPT], my_b[P1_EPT];
#pragma unroll
    for (int j = 0; j < P1_EPT; ++j) {
        int idx = t + j * 256;
        if (idx < cnt) {
            my_s[j] = src[base + idx];
            my_d[j] = dst[base + idx];
            my_b[j] = my_d[j] >> 8;
            atomicAdd(&lcount[my_b[j]], 1);
        } else my_b[j] = -1;
    }
    __syncthreads();

    // exclusive scan of lcount -> lstart
    int v = lcount[t];
    lstart[t] = v;
    __syncthreads();
#pragma unroll
    for (int d = 1; d < 256; d <<= 1) {
        int nv = (t >= d) ? lstart[t - d] : 0;
        __syncthreads();
        lstart[t] += nv;
        __syncthreads();
    }
    int excl = lstart[t] - v;
    __syncthreads();
    lstart[t] = excl;
    // reserve global space for this block's bucket segments
    lresv[t] = (t < NBUCK && v > 0) ? atomicAdd(&gcursor[t], v) : 0;
    lcount[t] = 0;
    __syncthreads();

    // place pairs into LDS staging
#pragma unroll
    for (int j = 0; j < P1_EPT; ++j) {
        if (my_b[j] >= 0) {
            int lpos = lstart[my_b[j]] + atomicAdd(&lcount[my_b[j]], 1);
            stage[lpos] = ((unsigned long long)(unsigned)my_d[j] << 32) | (unsigned)my_s[j];
        }
    }
    __syncthreads();

    // copy staged segments to global (dense, mostly coalesced)
    for (int sl = t; sl < cnt; sl += 256) {
        unsigned long long pr = stage[sl];
        int d_ = (int)(pr >> 32);
        int b_ = d_ >> 8;
        int g = lresv[b_] + (sl - lstart[b_]);
        pairs[g] = pr;
    }
}

// ---------------------------------------------------------------- pass 2: bucket -> final CSR
// One block per bucket; 256 LDS cursors; writes confined to the bucket's CSR region.
__global__ __launch_bounds__(256) void k_csr(const unsigned long long* __restrict__ pairs,
                                             const int* __restrict__ off,
                                             int* __restrict__ src_s) {
    __shared__ int cur[256];
    int b = blockIdx.x, t = threadIdx.x;
    int nb0 = b * 256;
    int nb1 = nb0 + 256; if (nb1 > N_NODES) nb1 = N_NODES;
    int e0 = off[nb0], e1 = off[nb1];
    cur[t] = 0;
    __syncthreads();
    for (int e = e0 + t; e < e1; e += 256) {
        unsigned long long pr = pairs[e];
        int d_ = (int)(pr >> 32);
        int s_ = (int)(pr & 0xffffffffu);
        int pos = off[d_] + atomicAdd(&cur[d_ & 255], 1);
        src_s[pos] = s_;
    }
}

// ---------------------------------------------------------------- fused 4-matrix MFMA GEMM
// q -> bf16; k,v -> fp8 e4m3 interleaved [node][k128B|v128B]; skip -> bf16
__global__ __launch_bounds__(256) void k_gemm_fused(
    const __bf16* __restrict__ Xb,
    const __bf16* __restrict__ Wq, const __bf16* __restrict__ Wk,
    const __bf16* __restrict__ Wv, const __bf16* __restrict__ Wsk,
    const float* __restrict__ Bq, const float* __restrict__ Bk,
    const float* __restrict__ Bv, const float* __restrict__ Bs,
    __bf16* __restrict__ Oq, unsigned char* __restrict__ Okv,
    __bf16* __restrict__ Osk) {
    int t = threadIdx.x;
    int wsel = t >> 6, l = t & 63;
    int lo5 = l & 31, hi = l >> 5;
    int row0 = blockIdx.x * 32;

    const __bf16* W = (wsel == 0) ? Wq : (wsel == 1) ? Wk : (wsel == 2) ? Wv : Wsk;
    const float*  B = (wsel == 0) ? Bq : (wsel == 1) ? Bk : (wsel == 2) ? Bv : Bs;

    const bf16x8* arow = (const bf16x8*)(Xb + (size_t)(row0 + lo5) * DIM + hi * 8);
    bf16x8 a[8];
#pragma unroll
    for (int kt = 0; kt < 8; ++kt) a[kt] = arow[kt * 2];

#pragma unroll
    for (int ct = 0; ct < 4; ++ct) {
        int col0 = ct * 32;
        const bf16x8* brow = (const bf16x8*)(W + (size_t)(col0 + lo5) * DIM + hi * 8);
        f32x16 acc = {};
#pragma unroll
        for (int kt = 0; kt < 8; ++kt)
            acc = __builtin_amdgcn_mfma_f32_32x32x16_bf16(a[kt], brow[kt * 2], acc, 0, 0, 0);

        float bias = B[col0 + lo5];
        if (wsel == 3) {
#pragma unroll
            for (int r = 0; r < 16; ++r) {
                int row = row0 + (r & 3) + 8 * (r >> 2) + 4 * hi;
                if (row < N_NODES)
                    Osk[(size_t)row * DIM + col0 + lo5] = (__bf16)(acc[r] + bias);
            }
        } else if (wsel == 0) {
#pragma unroll
            for (int r = 0; r < 16; ++r) {
                int row = row0 + (r & 3) + 8 * (r >> 2) + 4 * hi;
                if (row < N_NODES)
                    Oq[(size_t)row * DIM + col0 + lo5] = (__bf16)(acc[r] + bias);
            }
        } else {
            int coff = (wsel == 2) ? 128 : 0;   // k at +0, v at +128 bytes
#pragma unroll
            for (int r = 0; r < 16; ++r) {
                int row = row0 + (r & 3) + 8 * (r >> 2) + 4 * hi;
                if (row < N_NODES) {
                    __hip_fp8_e4m3 t8((float)(acc[r] + bias));
                    Okv[(size_t)row * 256 + coff + col0 + lo5] = t8.__x;
                }
            }
        }
    }
}

// ---------------------------------------------------------------- fused alpha + softmax + aggregate (+skip+relu)
// One node per WAVE; 4x16-lane groups, 2-edge unroll, fp8 k/v, no-max softmax.
__global__ __launch_bounds__(256) void k_edge_fused(const __bf16* __restrict__ q,
                                                    const unsigned char* __restrict__ kv,
                                                    const __bf16* __restrict__ skip,
                                                    const int* __restrict__ src_s,
                                                    const int* __restrict__ off,
                                                    float* __restrict__ xout,
                                                    __bf16* __restrict__ xb,
                                                    int wf32) {
    int t = threadIdx.x;
    int wave = t >> 6, l = t & 63;
    int n = blockIdx.x * 4 + wave;               // 50000 = 12500 * 4
    if (n >= N_NODES) return;
    int g = l >> 4, gl = l & 15;                 // 4 groups of 16 lanes
    int start = off[n], end = off[n + 1];

    const float S = 0.08838834764831845f;        // 1/sqrt(128), folded into q
    float qf[8];
    {
        bf16x8 qv = *(const bf16x8*)(q + (size_t)n * DIM + gl * 8);
#pragma unroll
        for (int j = 0; j < 8; ++j) qf[j] = (float)qv[j] * S;
    }

    float denom = 0.f;
    float facc[8] = {};

    for (int e = start + g; e < end; e += 8) {
        int s0 = src_s[e];
        bool h1 = (e + 4 < end);
        int s1 = h1 ? src_s[e + 4] : s0;
        const unsigned char* r0 = kv + (size_t)s0 * 256 + gl * 8;
        const unsigned char* r1 = kv + (size_t)s1 * 256 + gl * 8;
        U8 k0u, k1u, v0u, v1u;
        k0u.u = *(const uint2*)(r0);
        k1u.u = *(const uint2*)(r1);
        v0u.u = *(const uint2*)(r0 + 128);
        v1u.u = *(const uint2*)(r1 + 128);

        float k0f[8], k1f[8];
        cvt8_fp8_f32(k0u, k0f);
        cvt8_fp8_f32(k1u, k1f);
        float p0 = 0.f, p1 = 0.f;
#pragma unroll
        for (int j = 0; j < 8; ++j) {
            p0 += qf[j] * k0f[j];
            p1 += qf[j] * k1f[j];
        }
        p0 += __shfl_xor(p0, 8, 16);  p1 += __shfl_xor(p1, 8, 16);
        p0 += __shfl_xor(p0, 4, 16);  p1 += __shfl_xor(p1, 4, 16);
        p0 += __shfl_xor(p0, 2, 16);  p1 += __shfl_xor(p1, 2, 16);
        p0 += __shfl_xor(p0, 1, 16);  p1 += __shfl_xor(p1, 1, 16);
        p0 = fminf(p0, 80.f);
        p1 = h1 ? fminf(p1, 80.f) : -INFINITY;

        float w0 = __expf(p0);
        float w1 = __expf(p1);
        denom += w0 + w1;

        float v0f[8], v1f[8];
        cvt8_fp8_f32(v0u, v0f);
        cvt8_fp8_f32(v1u, v1f);
#pragma unroll
        for (int j = 0; j < 8; ++j)
            facc[j] += w0 * v0f[j] + w1 * v1f[j];
    }

#pragma unroll
    for (int dlt = 16; dlt <= 32; dlt <<= 1) {
        denom += __shfl_xor(denom, dlt, 64);
#pragma unroll
        for (int j = 0; j < 8; ++j) facc[j] += __shfl_xor(facc[j], dlt, 64);
    }
    float inv = (denom > 0.f) ? 1.f / denom : 0.f;

    if (g == 0) {
        bf16x8 sk = *(const bf16x8*)(skip + (size_t)n * DIM + gl * 8);
        float o[8];
        bf16x8 ob;
#pragma unroll
        for (int j = 0; j < 8; ++j) {
            float val = fmaxf((float)sk[j] + facc[j] * inv, 0.f);
            o[j] = val; ob[j] = (__bf16)val;
        }
        if (wf32) {
            float* xrow = xout + (size_t)n * DIM + gl * 8;
            *(float4*)(xrow)     = make_float4(o[0], o[1], o[2], o[3]);
            *(float4*)(xrow + 4) = make_float4(o[4], o[5], o[6], o[7]);
        }
        *(bf16x8*)(xb + (size_t)n * DIM + gl * 8) = ob;
    }
}

// ---------------------------------------------------------------- mean pool
__global__ __launch_bounds__(256) void k_pool(const float* __restrict__ x,
                                              const int* __restrict__ batch,
                                              float* __restrict__ out) {
    __shared__ float sacc[4][DIM];
    int g = blockIdx.x;
    int t = threadIdx.x;
    int w = t >> 6, l = t & 63;
    int lo = 0, hi = N_NODES;
    while (lo < hi) { int mid = (lo + hi) >> 1; if (batch[mid] < g) lo = mid + 1; else hi = mid; }
    int s0 = lo;
    hi = N_NODES;
    while (lo < hi) { int mid = (lo + hi) >> 1; if (batch[mid] < g + 1) lo = mid + 1; else hi = mid; }
    int s1 = lo;
    float a0 = 0.f, a1 = 0.f;
    for (int n = s0 + w; n < s1; n += 4) {
        float2 xr = *(const float2*)(x + (size_t)n * DIM + l * 2);
        a0 += xr.x; a1 += xr.y;
    }
    sacc[w][l * 2] = a0; sacc[w][l * 2 + 1] = a1;
    __syncthreads();
    if (t < DIM) {
        float s = sacc[0][t] + sacc[1][t] + sacc[2][t] + sacc[3][t];
        int cnt = s1 - s0;
        out[(size_t)g * DIM + t] = s / (float)((cnt > 0) ? cnt : 1);
    }
}

// ----------------------------------------------------------------
extern "C" void kernel_launch(void* const* d_in, const int* in_sizes, int n_in,
                              void* d_out, int out_size, void* d_ws, size_t ws_size,
                              hipStream_t stream) {
    const float* x0   = (const float*)d_in[0];
    const int*  eidx  = (const int*)d_in[1];
    const int*  batch = (const int*)d_in[2];
    const float* Wq = (const float*)d_in[3];
    const float* bq = (const float*)d_in[4];
    const float* Wk = (const float*)d_in[5];
    const float* bk = (const float*)d_in[6];
    const float* Wv = (const float*)d_in[7];
    const float* bv = (const float*)d_in[8];
    const float* Ws = (const float*)d_in[9];
    const float* bs = (const float*)d_in[10];
    float* out = (float*)d_out;

    const int* src = eidx;
    const int* dst = eidx + N_EDGES;

    char* ws = (char*)d_ws;
    size_t p = 0;
    auto alloc = [&](size_t bytes) -> void* {
        void* r = ws + p;
        p = (p + bytes + 255) & ~(size_t)255;
        return r;
    };
    int*    off    = (int*)alloc((N_NODES + 1) * sizeof(int));
    int*    cnt    = (int*)alloc(N_NODES * sizeof(int));
    int*    bsum   = (int*)alloc(256 * sizeof(int));
    int*    boff   = (int*)alloc(256 * sizeof(int));
    int*    gcur   = (int*)alloc(256 * sizeof(int));
    int*    src_s  = (int*)alloc(N_EDGES * sizeof(int));
    unsigned long long* prs = (unsigned long long*)alloc((size_t)N_EDGES * 8);
    __bf16* Xb     = (__bf16*)alloc((size_t)N_NODES * DIM * sizeof(__bf16));
    __bf16* qb     = (__bf16*)alloc((size_t)N_NODES * DIM * sizeof(__bf16));
    unsigned char* kvb = (unsigned char*)alloc((size_t)N_NODES * 256);
    __bf16* skb    = (__bf16*)alloc((size_t)N_NODES * DIM * sizeof(__bf16));
    float*  s1     = (float*)alloc((size_t)N_NODES * DIM * sizeof(float));
    __bf16* Wqb    = (__bf16*)alloc((size_t)NLAYERS * DIM * DIM * sizeof(__bf16));
    __bf16* Wkb    = (__bf16*)alloc((size_t)NLAYERS * DIM * DIM * sizeof(__bf16));
    __bf16* Wvb    = (__bf16*)alloc((size_t)NLAYERS * DIM * DIM * sizeof(__bf16));
    __bf16* Wsb    = (__bf16*)alloc((size_t)NLAYERS * DIM * DIM * sizeof(__bf16));

    // ---- casts
    {
        int nx = N_NODES * DIM;
        k_cast<<<(nx / 8 + 255) / 256, 256, 0, stream>>>(x0, Xb, nx);
        int nw = NLAYERS * DIM * DIM;
        dim3 gw((nw / 8 + 255) / 256, 4);
        k_cast4<<<gw, 256, 0, stream>>>(Wq, Wk, Wv, Ws, Wqb, Wkb, Wvb, Wsb, nw);
    }

    // ---- build CSR (degree -> scan -> LDS-staged 2-pass bucket sort)
    hipMemsetAsync(cnt, 0, N_NODES * sizeof(int), stream);
    k_degree<<<(N_EDGES + 255) / 256, 256, 0, stream>>>(dst, cnt);
    k_scan1<<<SCAN_NB, 256, 0, stream>>>(cnt, off, bsum);
    k_scan2<<<1, 256, 0, stream>>>(bsum, boff, off + N_NODES);
    k_scan3<<<SCAN_NB, 256, 0, stream>>>(off, boff);
    k_ginit<<<1, 256, 0, stream>>>(off, gcur);
    k_bucket<<<P1_NB, 256, 0, stream>>>(src, dst, gcur, prs);
    k_csr<<<NBUCK, 256, 0, stream>>>(prs, off, src_s);

    // ---- layers
    for (int l = 0; l < NLAYERS; ++l) {
        const __bf16* wq = Wqb + (size_t)l * DIM * DIM;
        const __bf16* wk = Wkb + (size_t)l * DIM * DIM;
        const __bf16* wv = Wvb + (size_t)l * DIM * DIM;
        const __bf16* wsk = Wsb + (size_t)l * DIM * DIM;
        const float* biq = bq + (size_t)l * DIM;
        const float* bik = bk + (size_t)l * DIM;
        const float* biv = bv + (size_t)l * DIM;
        const float* bis = bs + (size_t)l * DIM;

        k_gemm_fused<<<(N_NODES + 31) / 32, 256, 0, stream>>>(Xb, wq, wk, wv, wsk,
                                                              biq, bik, biv, bis,
                                                              qb, kvb, skb);
        int wf32 = (l == NLAYERS - 1) ? 1 : 0;
        k_edge_fused<<<(N_NODES + 3) / 4, 256, 0, stream>>>(qb, kvb, skb, src_s, off,
                                                            s1, Xb, wf32);
    }

    // ---- mean pool
    k_pool<<<NGRAPH, 256, 0, stream>>>(s1, batch, out);
}

// Round 12
// 341.506 us; speedup vs baseline: 1.3861x; 1.0454x over previous
//
#include <hip/hip_runtime.h>
#include <hip/hip_fp8.h>

#define N_NODES 50000
#define N_EDGES 800000
#define DIM 128
#define NLAYERS 3
#define NGRAPH 512
#define SCAN_NB ((N_NODES + 255) / 256)   // 196
#define NBUCK   ((N_NODES + 255) / 256)   // 196 buckets of 256 nodes (dst>>8)
#define P1_CHUNK 2048
#define P1_EPT   8                         // 2048 / 256
#define P1_NB    ((N_EDGES + P1_CHUNK - 1) / P1_CHUNK)   // 391

typedef __attribute__((ext_vector_type(8)))  __bf16 bf16x8;
typedef __attribute__((ext_vector_type(16))) float  f32x16;
typedef __attribute__((ext_vector_type(2)))  float  f32x2;

union U8 { uint2 u; unsigned char b[8]; };

// 8 fp8 (e4m3, OCP on gfx950) -> 4x float2, packed HW cvt when available
__device__ inline void cvt8_pk(U8 x, f32x2* f) {
#if defined(__has_builtin) && __has_builtin(__builtin_amdgcn_cvt_pk_f32_fp8)
    f[0] = __builtin_amdgcn_cvt_pk_f32_fp8(x.u.x, false);
    f[1] = __builtin_amdgcn_cvt_pk_f32_fp8(x.u.x, true);
    f[2] = __builtin_amdgcn_cvt_pk_f32_fp8(x.u.y, false);
    f[3] = __builtin_amdgcn_cvt_pk_f32_fp8(x.u.y, true);
#else
#pragma unroll
    for (int j = 0; j < 4; ++j) {
        __hip_fp8_e4m3 a; a.__x = x.b[2 * j];
        __hip_fp8_e4m3 c; c.__x = x.b[2 * j + 1];
        f32x2 r; r[0] = (float)a; r[1] = (float)c;
        f[j] = r;
    }
#endif
}

// ---------------------------------------------------------------- fp32 -> bf16 cast
__global__ __launch_bounds__(256) void k_cast(const float* __restrict__ in,
                                              __bf16* __restrict__ out, int n) {
    int i = blockIdx.x * blockDim.x + threadIdx.x;
    int base = i * 8;
    if (base >= n) return;
    float4 a = *(const float4*)(in + base);
    float4 b = *(const float4*)(in + base + 4);
    bf16x8 o;
    o[0] = (__bf16)a.x; o[1] = (__bf16)a.y; o[2] = (__bf16)a.z; o[3] = (__bf16)a.w;
    o[4] = (__bf16)b.x; o[5] = (__bf16)b.y; o[6] = (__bf16)b.z; o[7] = (__bf16)b.w;
    *(bf16x8*)(out + base) = o;
}

// 4 weight tensors in one launch (blockIdx.y selects)
__global__ __launch_bounds__(256) void k_cast4(
    const float* __restrict__ i0, const float* __restrict__ i1,
    const float* __restrict__ i2, const float* __restrict__ i3,
    __bf16* __restrict__ o0, __bf16* __restrict__ o1,
    __bf16* __restrict__ o2, __bf16* __restrict__ o3, int n) {
    int sel = blockIdx.y;
    const float* in = (sel == 0) ? i0 : (sel == 1) ? i1 : (sel == 2) ? i2 : i3;
    __bf16* out     = (sel == 0) ? o0 : (sel == 1) ? o1 : (sel == 2) ? o2 : o3;
    int i = blockIdx.x * blockDim.x + threadIdx.x;
    int base = i * 8;
    if (base >= n) return;
    float4 a = *(const float4*)(in + base);
    float4 b = *(const float4*)(in + base + 4);
    bf16x8 o;
    o[0] = (__bf16)a.x; o[1] = (__bf16)a.y; o[2] = (__bf16)a.z; o[3] = (__bf16)a.w;
    o[4] = (__bf16)b.x; o[5] = (__bf16)b.y; o[6] = (__bf16)b.z; o[7] = (__bf16)b.w;
    *(bf16x8*)(out + base) = o;
}

// ---------------------------------------------------------------- degree
__global__ __launch_bounds__(256) void k_degree(const int* __restrict__ dst,
                                                int* __restrict__ cnt) {
    int i = blockIdx.x * blockDim.x + threadIdx.x;
    if (i < N_EDGES) atomicAdd(&cnt[dst[i]], 1);
}

// ---------------------------------------------------------------- hierarchical scan
__global__ __launch_bounds__(256) void k_scan1(const int* __restrict__ cnt,
                                               int* __restrict__ off,
                                               int* __restrict__ bsum) {
    __shared__ int s[256];
    int b = blockIdx.x, t = threadIdx.x;
    int i = b * 256 + t;
    int v = (i < N_NODES) ? cnt[i] : 0;
    s[t] = v; __syncthreads();
#pragma unroll
    for (int d = 1; d < 256; d <<= 1) {
        int nv = (t >= d) ? s[t - d] : 0;
        __syncthreads();
        s[t] += nv;
        __syncthreads();
    }
    if (i < N_NODES) off[i] = s[t] - v;
    if (t == 255) bsum[b] = s[255];
}

__global__ __launch_bounds__(256) void k_scan2(const int* __restrict__ bsum,
                                               int* __restrict__ boff,
                                               int* __restrict__ offN) {
    __shared__ int s[256];
    int t = threadIdx.x;
    int v = (t < SCAN_NB) ? bsum[t] : 0;
    s[t] = v; __syncthreads();
#pragma unroll
    for (int d = 1; d < 256; d <<= 1) {
        int nv = (t >= d) ? s[t - d] : 0;
        __syncthreads();
        s[t] += nv;
        __syncthreads();
    }
    boff[t] = s[t] - v;
    if (t == 255) *offN = s[255];
}

__global__ __launch_bounds__(256) void k_scan3(int* __restrict__ off,
                                               const int* __restrict__ boff) {
    int b = blockIdx.x, t = threadIdx.x;
    int i = b * 256 + t;
    if (i < N_NODES) off[i] += boff[b];
}

// ---------------------------------------------------------------- gcursor init (bucket bases)
__global__ __launch_bounds__(256) void k_ginit(const int* __restrict__ off,
                                               int* __restrict__ gcursor) {
    int t = threadIdx.x;
    if (t < NBUCK) gcursor[t] = off[t * 256];
}

// ---------------------------------------------------------------- pass 1: LDS-staged bucket binning
__global__ __launch_bounds__(256) void k_bucket(const int* __restrict__ src,
                                                const int* __restrict__ dst,
                                                int* __restrict__ gcursor,
                                                unsigned long long* __restrict__ pairs) {
    __shared__ int lcount[256];
    __shared__ int lstart[256];
    __shared__ int lresv[256];
    __shared__ unsigned long long stage[P1_CHUNK];   // 16 KB
    int t = threadIdx.x;
    int base = blockIdx.x * P1_CHUNK;
    int cnt = N_EDGES - base; if (cnt > P1_CHUNK) cnt = P1_CHUNK;

    lcount[t] = 0;
    __syncthreads();

    int my_s[P1_EPT], my_d[P1_EPT], my_b[P1_EPT];
#pragma unroll
    for (int j = 0; j < P1_EPT; ++j) {
        int idx = t + j * 256;
        if (idx < cnt) {
            my_s[j] = src[base + idx];
            my_d[j] = dst[base + idx];
            my_b[j] = my_d[j] >> 8;
            atomicAdd(&lcount[my_b[j]], 1);
        } else my_b[j] = -1;
    }
    __syncthreads();

    int v = lcount[t];
    lstart[t] = v;
    __syncthreads();
#pragma unroll
    for (int d = 1; d < 256; d <<= 1) {
        int nv = (t >= d) ? lstart[t - d] : 0;
        __syncthreads();
        lstart[t] += nv;
        __syncthreads();
    }
    int excl = lstart[t] - v;
    __syncthreads();
    lstart[t] = excl;
    lresv[t] = (t < NBUCK && v > 0) ? atomicAdd(&gcursor[t], v) : 0;
    lcount[t] = 0;
    __syncthreads();

#pragma unroll
    for (int j = 0; j < P1_EPT; ++j) {
        if (my_b[j] >= 0) {
            int lpos = lstart[my_b[j]] + atomicAdd(&lcount[my_b[j]], 1);
            stage[lpos] = ((unsigned long long)(unsigned)my_d[j] << 32) | (unsigned)my_s[j];
        }
    }
    __syncthreads();

    for (int sl = t; sl < cnt; sl += 256) {
        unsigned long long pr = stage[sl];
        int d_ = (int)(pr >> 32);
        int b_ = d_ >> 8;
        int g = lresv[b_] + (sl - lstart[b_]);
        pairs[g] = pr;
    }
}

// ---------------------------------------------------------------- pass 2: bucket -> final CSR
__global__ __launch_bounds__(256) void k_csr(const unsigned long long* __restrict__ pairs,
                                             const int* __restrict__ off,
                                             int* __restrict__ src_s) {
    __shared__ int cur[256];
    int b = blockIdx.x, t = threadIdx.x;
    int nb0 = b * 256;
    int nb1 = nb0 + 256; if (nb1 > N_NODES) nb1 = N_NODES;
    int e0 = off[nb0], e1 = off[nb1];
    cur[t] = 0;
    __syncthreads();
    for (int e = e0 + t; e < e1; e += 256) {
        unsigned long long pr = pairs[e];
        int d_ = (int)(pr >> 32);
        int s_ = (int)(pr & 0xffffffffu);
        int pos = off[d_] + atomicAdd(&cur[d_ & 255], 1);
        src_s[pos] = s_;
    }
}

// ---------------------------------------------------------------- fused 4-matrix MFMA GEMM
// q -> bf16; k,v -> fp8 e4m3 interleaved [node][k128B|v128B]; skip -> bf16
__global__ __launch_bounds__(256) void k_gemm_fused(
    const __bf16* __restrict__ Xb,
    const __bf16* __restrict__ Wq, const __bf16* __restrict__ Wk,
    const __bf16* __restrict__ Wv, const __bf16* __restrict__ Wsk,
    const float* __restrict__ Bq, const float* __restrict__ Bk,
    const float* __restrict__ Bv, const float* __restrict__ Bs,
    __bf16* __restrict__ Oq, unsigned char* __restrict__ Okv,
    __bf16* __restrict__ Osk) {
    int t = threadIdx.x;
    int wsel = t >> 6, l = t & 63;
    int lo5 = l & 31, hi = l >> 5;
    int row0 = blockIdx.x * 32;

    const __bf16* W = (wsel == 0) ? Wq : (wsel == 1) ? Wk : (wsel == 2) ? Wv : Wsk;
    const float*  B = (wsel == 0) ? Bq : (wsel == 1) ? Bk : (wsel == 2) ? Bv : Bs;

    const bf16x8* arow = (const bf16x8*)(Xb + (size_t)(row0 + lo5) * DIM + hi * 8);
    bf16x8 a[8];
#pragma unroll
    for (int kt = 0; kt < 8; ++kt) a[kt] = arow[kt * 2];

#pragma unroll
    for (int ct = 0; ct < 4; ++ct) {
        int col0 = ct * 32;
        const bf16x8* brow = (const bf16x8*)(W + (size_t)(col0 + lo5) * DIM + hi * 8);
        f32x16 acc = {};
#pragma unroll
        for (int kt = 0; kt < 8; ++kt)
            acc = __builtin_amdgcn_mfma_f32_32x32x16_bf16(a[kt], brow[kt * 2], acc, 0, 0, 0);

        float bias = B[col0 + lo5];
        if (wsel == 3) {
#pragma unroll
            for (int r = 0; r < 16; ++r) {
                int row = row0 + (r & 3) + 8 * (r >> 2) + 4 * hi;
                if (row < N_NODES)
                    Osk[(size_t)row * DIM + col0 + lo5] = (__bf16)(acc[r] + bias);
            }
        } else if (wsel == 0) {
#pragma unroll
            for (int r = 0; r < 16; ++r) {
                int row = row0 + (r & 3) + 8 * (r >> 2) + 4 * hi;
                if (row < N_NODES)
                    Oq[(size_t)row * DIM + col0 + lo5] = (__bf16)(acc[r] + bias);
            }
        } else {
            int coff = (wsel == 2) ? 128 : 0;   // k at +0, v at +128 bytes
#pragma unroll
            for (int r = 0; r < 16; ++r) {
                int row = row0 + (r & 3) + 8 * (r >> 2) + 4 * hi;
                if (row < N_NODES) {
                    __hip_fp8_e4m3 t8((float)(acc[r] + bias));
                    Okv[(size_t)row * 256 + coff + col0 + lo5] = t8.__x;
                }
            }
        }
    }
}

// ---------------------------------------------------------------- fused alpha + softmax + aggregate (+skip+relu)
// One node per WAVE; 4x16-lane groups, 2-edge unroll, fp8 k/v via packed HW cvt,
// packed f32 math (v_pk_fma), no-max softmax.
__global__ __launch_bounds__(256) void k_edge_fused(const __bf16* __restrict__ q,
                                                    const unsigned char* __restrict__ kv,
                                                    const __bf16* __restrict__ skip,
                                                    const int* __restrict__ src_s,
                                                    const int* __restrict__ off,
                                                    float* __restrict__ xout,
                                                    __bf16* __restrict__ xb,
                                                    int wf32) {
    int t = threadIdx.x;
    int wave = t >> 6, l = t & 63;
    int n = blockIdx.x * 4 + wave;               // 50000 = 12500 * 4
    if (n >= N_NODES) return;
    int g = l >> 4, gl = l & 15;                 // 4 groups of 16 lanes
    int start = off[n], end = off[n + 1];

    const float S = 0.08838834764831845f;        // 1/sqrt(128), folded into q
    f32x2 qf[4];
    {
        bf16x8 qv = *(const bf16x8*)(q + (size_t)n * DIM + gl * 8);
#pragma unroll
        for (int j = 0; j < 4; ++j) {
            f32x2 r;
            r[0] = (float)qv[2 * j] * S;
            r[1] = (float)qv[2 * j + 1] * S;
            qf[j] = r;
        }
    }

    float denom = 0.f;
    f32x2 facc[4] = {};

    for (int e = start + g; e < end; e += 8) {   // this group's edges, 2 per iter
        int s0 = src_s[e];
        bool h1 = (e + 4 < end);
        int s1 = h1 ? src_s[e + 4] : s0;         // dummy (w1 forced to 0)
        const unsigned char* r0 = kv + (size_t)s0 * 256 + gl * 8;
        const unsigned char* r1 = kv + (size_t)s1 * 256 + gl * 8;
        U8 k0u, k1u, v0u, v1u;
        k0u.u = *(const uint2*)(r0);
        k1u.u = *(const uint2*)(r1);
        v0u.u = *(const uint2*)(r0 + 128);
        v1u.u = *(const uint2*)(r1 + 128);

        f32x2 k0f[4], k1f[4];
        cvt8_pk(k0u, k0f);
        cvt8_pk(k1u, k1f);
        f32x2 d0 = qf[0] * k0f[0];
        f32x2 d1 = qf[0] * k1f[0];
        d0 += qf[1] * k0f[1];  d1 += qf[1] * k1f[1];
        d0 += qf[2] * k0f[2];  d1 += qf[2] * k1f[2];
        d0 += qf[3] * k0f[3];  d1 += qf[3] * k1f[3];
        float p0 = d0[0] + d0[1];
        float p1 = d1[0] + d1[1];
        p0 += __shfl_xor(p0, 8, 16);  p1 += __shfl_xor(p1, 8, 16);
        p0 += __shfl_xor(p0, 4, 16);  p1 += __shfl_xor(p1, 4, 16);
        p0 += __shfl_xor(p0, 2, 16);  p1 += __shfl_xor(p1, 2, 16);
        p0 += __shfl_xor(p0, 1, 16);  p1 += __shfl_xor(p1, 1, 16);
        p0 = fminf(p0, 80.f);                    // overflow insurance only
        p1 = h1 ? fminf(p1, 80.f) : -INFINITY;

        float w0 = __expf(p0);
        float w1 = __expf(p1);                   // exp(-inf) = 0 kills the tail slot
        denom += w0 + w1;

        f32x2 v0f[4], v1f[4];
        cvt8_pk(v0u, v0f);
        cvt8_pk(v1u, v1f);
        f32x2 w02; w02[0] = w0; w02[1] = w0;
        f32x2 w12; w12[0] = w1; w12[1] = w1;
#pragma unroll
        for (int j = 0; j < 4; ++j)
            facc[j] += w02 * v0f[j] + w12 * v1f[j];
    }

    // merge the 4 groups: plain adds
#pragma unroll
    for (int dlt = 16; dlt <= 32; dlt <<= 1) {
        denom += __shfl_xor(denom, dlt, 64);
#pragma unroll
        for (int j = 0; j < 4; ++j) {
            f32x2 o;
            o[0] = __shfl_xor(facc[j][0], dlt, 64);
            o[1] = __shfl_xor(facc[j][1], dlt, 64);
            facc[j] += o;
        }
    }
    float inv = (denom > 0.f) ? 1.f / denom : 0.f;

    if (g == 0) {
        bf16x8 sk = *(const bf16x8*)(skip + (size_t)n * DIM + gl * 8);
        float o[8];
        bf16x8 ob;
#pragma unroll
        for (int j = 0; j < 8; ++j) {
            float f = facc[j >> 1][j & 1];
            float val = fmaxf((float)sk[j] + f * inv, 0.f);
            o[j] = val; ob[j] = (__bf16)val;
        }
        if (wf32) {
            float* xrow = xout + (size_t)n * DIM + gl * 8;
            *(float4*)(xrow)     = make_float4(o[0], o[1], o[2], o[3]);
            *(float4*)(xrow + 4) = make_float4(o[4], o[5], o[6], o[7]);
        }
        *(bf16x8*)(xb + (size_t)n * DIM + gl * 8) = ob;
    }
}

// ---------------------------------------------------------------- mean pool
__global__ __launch_bounds__(256) void k_pool(const float* __restrict__ x,
                                              const int* __restrict__ batch,
                                              float* __restrict__ out) {
    __shared__ float sacc[4][DIM];
    int g = blockIdx.x;
    int t = threadIdx.x;
    int w = t >> 6, l = t & 63;
    int lo = 0, hi = N_NODES;
    while (lo < hi) { int mid = (lo + hi) >> 1; if (batch[mid] < g) lo = mid + 1; else hi = mid; }
    int s0 = lo;
    hi = N_NODES;
    while (lo < hi) { int mid = (lo + hi) >> 1; if (batch[mid] < g + 1) lo = mid + 1; else hi = mid; }
    int s1 = lo;
    float a0 = 0.f, a1 = 0.f;
    for (int n = s0 + w; n < s1; n += 4) {
        float2 xr = *(const float2*)(x + (size_t)n * DIM + l * 2);
        a0 += xr.x; a1 += xr.y;
    }
    sacc[w][l * 2] = a0; sacc[w][l * 2 + 1] = a1;
    __syncthreads();
    if (t < DIM) {
        float s = sacc[0][t] + sacc[1][t] + sacc[2][t] + sacc[3][t];
        int cnt = s1 - s0;
        out[(size_t)g * DIM + t] = s / (float)((cnt > 0) ? cnt : 1);
    }
}

// ----------------------------------------------------------------
extern "C" void kernel_launch(void* const* d_in, const int* in_sizes, int n_in,
                              void* d_out, int out_size, void* d_ws, size_t ws_size,
                              hipStream_t stream) {
    const float* x0   = (const float*)d_in[0];
    const int*  eidx  = (const int*)d_in[1];
    const int*  batch = (const int*)d_in[2];
    const float* Wq = (const float*)d_in[3];
    const float* bq = (const float*)d_in[4];
    const float* Wk = (const float*)d_in[5];
    const float* bk = (const float*)d_in[6];
    const float* Wv = (const float*)d_in[7];
    const float* bv = (const float*)d_in[8];
    const float* Ws = (const float*)d_in[9];
    const float* bs = (const float*)d_in[10];
    float* out = (float*)d_out;

    const int* src = eidx;
    const int* dst = eidx + N_EDGES;

    char* ws = (char*)d_ws;
    size_t p = 0;
    auto alloc = [&](size_t bytes) -> void* {
        void* r = ws + p;
        p = (p + bytes + 255) & ~(size_t)255;
        return r;
    };
    int*    off    = (int*)alloc((N_NODES + 1) * sizeof(int));
    int*    cnt    = (int*)alloc(N_NODES * sizeof(int));
    int*    bsum   = (int*)alloc(256 * sizeof(int));
    int*    boff   = (int*)alloc(256 * sizeof(int));
    int*    gcur   = (int*)alloc(256 * sizeof(int));
    int*    src_s  = (int*)alloc(N_EDGES * sizeof(int));
    unsigned long long* prs = (unsigned long long*)alloc((size_t)N_EDGES * 8);
    __bf16* Xb     = (__bf16*)alloc((size_t)N_NODES * DIM * sizeof(__bf16));
    __bf16* qb     = (__bf16*)alloc((size_t)N_NODES * DIM * sizeof(__bf16));
    unsigned char* kvb = (unsigned char*)alloc((size_t)N_NODES * 256);
    __bf16* skb    = (__bf16*)alloc((size_t)N_NODES * DIM * sizeof(__bf16));
    float*  s1     = (float*)alloc((size_t)N_NODES * DIM * sizeof(float));
    __bf16* Wqb    = (__bf16*)alloc((size_t)NLAYERS * DIM * DIM * sizeof(__bf16));
    __bf16* Wkb    = (__bf16*)alloc((size_t)NLAYERS * DIM * DIM * sizeof(__bf16));
    __bf16* Wvb    = (__bf16*)alloc((size_t)NLAYERS * DIM * DIM * sizeof(__bf16));
    __bf16* Wsb    = (__bf16*)alloc((size_t)NLAYERS * DIM * DIM * sizeof(__bf16));

    // ---- casts
    {
        int nx = N_NODES * DIM;
        k_cast<<<(nx / 8 + 255) / 256, 256, 0, stream>>>(x0, Xb, nx);
        int nw = NLAYERS * DIM * DIM;
        dim3 gw((nw / 8 + 255) / 256, 4);
        k_cast4<<<gw, 256, 0, stream>>>(Wq, Wk, Wv, Ws, Wqb, Wkb, Wvb, Wsb, nw);
    }

    // ---- build CSR (degree -> scan -> LDS-staged 2-pass bucket sort)
    hipMemsetAsync(cnt, 0, N_NODES * sizeof(int), stream);
    k_degree<<<(N_EDGES + 255) / 256, 256, 0, stream>>>(dst, cnt);
    k_scan1<<<SCAN_NB, 256, 0, stream>>>(cnt, off, bsum);
    k_scan2<<<1, 256, 0, stream>>>(bsum, boff, off + N_NODES);
    k_scan3<<<SCAN_NB, 256, 0, stream>>>(off, boff);
    k_ginit<<<1, 256, 0, stream>>>(off, gcur);
    k_bucket<<<P1_NB, 256, 0, stream>>>(src, dst, gcur, prs);
    k_csr<<<NBUCK, 256, 0, stream>>>(prs, off, src_s);

    // ---- layers
    for (int l = 0; l < NLAYERS; ++l) {
        const __bf16* wq = Wqb + (size_t)l * DIM * DIM;
        const __bf16* wk = Wkb + (size_t)l * DIM * DIM;
        const __bf16* wv = Wvb + (size_t)l * DIM * DIM;
        const __bf16* wsk = Wsb + (size_t)l * DIM * DIM;
        const float* biq = bq + (size_t)l * DIM;
        const float* bik = bk + (size_t)l * DIM;
        const float* biv = bv + (size_t)l * DIM;
        const float* bis = bs + (size_t)l * DIM;

        k_gemm_fused<<<(N_NODES + 31) / 32, 256, 0, stream>>>(Xb, wq, wk, wv, wsk,
                                                              biq, bik, biv, bis,
                                                              qb, kvb, skb);
        int wf32 = (l == NLAYERS - 1) ? 1 : 0;
        k_edge_fused<<<(N_NODES + 3) / 4, 256, 0, stream>>>(qb, kvb, skb, src_s, off,
                                                            s1, Xb, wf32);
    }

    // ---- mean pool
    k_pool<<<NGRAPH, 256, 0, stream>>>(s1, batch, out);
}

// Round 13
// 337.969 us; speedup vs baseline: 1.4006x; 1.0105x over previous
//
#include <hip/hip_runtime.h>
#include <hip/hip_fp8.h>

#define N_NODES 50000
#define N_EDGES 800000
#define DIM 128
#define NLAYERS 3
#define NGRAPH 512
#define SCAN_NB ((N_NODES + 255) / 256)   // 196
#define NBUCK   ((N_NODES + 255) / 256)   // 196 buckets of 256 nodes (dst>>8)
#define P1_CHUNK 2048
#define P1_EPT   8                         // 2048 / 256
#define P1_NB    ((N_EDGES + P1_CHUNK - 1) / P1_CHUNK)   // 391

typedef __attribute__((ext_vector_type(8)))  __bf16 bf16x8;
typedef __attribute__((ext_vector_type(16))) float  f32x16;
typedef __attribute__((ext_vector_type(2)))  float  f32x2;

union U8 { uint2 u; unsigned char b[8]; };

// 8 fp8 (e4m3, OCP on gfx950) -> 4x float2, packed HW cvt when available
__device__ inline void cvt8_pk(U8 x, f32x2* f) {
#if defined(__has_builtin) && __has_builtin(__builtin_amdgcn_cvt_pk_f32_fp8)
    f[0] = __builtin_amdgcn_cvt_pk_f32_fp8(x.u.x, false);
    f[1] = __builtin_amdgcn_cvt_pk_f32_fp8(x.u.x, true);
    f[2] = __builtin_amdgcn_cvt_pk_f32_fp8(x.u.y, false);
    f[3] = __builtin_amdgcn_cvt_pk_f32_fp8(x.u.y, true);
#else
#pragma unroll
    for (int j = 0; j < 4; ++j) {
        __hip_fp8_e4m3 a; a.__x = x.b[2 * j];
        __hip_fp8_e4m3 c; c.__x = x.b[2 * j + 1];
        f32x2 r; r[0] = (float)a; r[1] = (float)c;
        f[j] = r;
    }
#endif
}

// 16 f32 -> 16 fp8 bytes (packed HW cvt when available)
__device__ inline uint4 pack16_fp8(const float* v) {
    uint4 r;
    unsigned int* pr = (unsigned int*)&r;
#if defined(__has_builtin) && __has_builtin(__builtin_amdgcn_cvt_pk_fp8_f32)
#pragma unroll
    for (int w = 0; w < 4; ++w) {
        int o = 0;
        o = __builtin_amdgcn_cvt_pk_fp8_f32(v[4 * w + 0], v[4 * w + 1], o, false);
        o = __builtin_amdgcn_cvt_pk_fp8_f32(v[4 * w + 2], v[4 * w + 3], o, true);
        pr[w] = (unsigned int)o;
    }
#else
#pragma unroll
    for (int w = 0; w < 4; ++w) {
        unsigned int o = 0;
#pragma unroll
        for (int j = 0; j < 4; ++j) {
            __hip_fp8_e4m3 t8(v[4 * w + j]);
            o |= ((unsigned int)t8.__x) << (8 * j);
        }
        pr[w] = o;
    }
#endif
    return r;
}

// ---------------------------------------------------------------- fp32 -> bf16 cast
__global__ __launch_bounds__(256) void k_cast(const float* __restrict__ in,
                                              __bf16* __restrict__ out, int n) {
    int i = blockIdx.x * blockDim.x + threadIdx.x;
    int base = i * 8;
    if (base >= n) return;
    float4 a = *(const float4*)(in + base);
    float4 b = *(const float4*)(in + base + 4);
    bf16x8 o;
    o[0] = (__bf16)a.x; o[1] = (__bf16)a.y; o[2] = (__bf16)a.z; o[3] = (__bf16)a.w;
    o[4] = (__bf16)b.x; o[5] = (__bf16)b.y; o[6] = (__bf16)b.z; o[7] = (__bf16)b.w;
    *(bf16x8*)(out + base) = o;
}

// 4 weight tensors in one launch (blockIdx.y selects)
__global__ __launch_bounds__(256) void k_cast4(
    const float* __restrict__ i0, const float* __restrict__ i1,
    const float* __restrict__ i2, const float* __restrict__ i3,
    __bf16* __restrict__ o0, __bf16* __restrict__ o1,
    __bf16* __restrict__ o2, __bf16* __restrict__ o3, int n) {
    int sel = blockIdx.y;
    const float* in = (sel == 0) ? i0 : (sel == 1) ? i1 : (sel == 2) ? i2 : i3;
    __bf16* out     = (sel == 0) ? o0 : (sel == 1) ? o1 : (sel == 2) ? o2 : o3;
    int i = blockIdx.x * blockDim.x + threadIdx.x;
    int base = i * 8;
    if (base >= n) return;
    float4 a = *(const float4*)(in + base);
    float4 b = *(const float4*)(in + base + 4);
    bf16x8 o;
    o[0] = (__bf16)a.x; o[1] = (__bf16)a.y; o[2] = (__bf16)a.z; o[3] = (__bf16)a.w;
    o[4] = (__bf16)b.x; o[5] = (__bf16)b.y; o[6] = (__bf16)b.z; o[7] = (__bf16)b.w;
    *(bf16x8*)(out + base) = o;
}

// ---------------------------------------------------------------- degree
__global__ __launch_bounds__(256) void k_degree(const int* __restrict__ dst,
                                                int* __restrict__ cnt) {
    int i = blockIdx.x * blockDim.x + threadIdx.x;
    if (i < N_EDGES) atomicAdd(&cnt[dst[i]], 1);
}

// ---------------------------------------------------------------- hierarchical scan
__global__ __launch_bounds__(256) void k_scan1(const int* __restrict__ cnt,
                                               int* __restrict__ off,
                                               int* __restrict__ bsum) {
    __shared__ int s[256];
    int b = blockIdx.x, t = threadIdx.x;
    int i = b * 256 + t;
    int v = (i < N_NODES) ? cnt[i] : 0;
    s[t] = v; __syncthreads();
#pragma unroll
    for (int d = 1; d < 256; d <<= 1) {
        int nv = (t >= d) ? s[t - d] : 0;
        __syncthreads();
        s[t] += nv;
        __syncthreads();
    }
    if (i < N_NODES) off[i] = s[t] - v;
    if (t == 255) bsum[b] = s[255];
}

__global__ __launch_bounds__(256) void k_scan2(const int* __restrict__ bsum,
                                               int* __restrict__ boff,
                                               int* __restrict__ offN) {
    __shared__ int s[256];
    int t = threadIdx.x;
    int v = (t < SCAN_NB) ? bsum[t] : 0;
    s[t] = v; __syncthreads();
#pragma unroll
    for (int d = 1; d < 256; d <<= 1) {
        int nv = (t >= d) ? s[t - d] : 0;
        __syncthreads();
        s[t] += nv;
        __syncthreads();
    }
    boff[t] = s[t] - v;
    if (t == 255) *offN = s[255];
}

__global__ __launch_bounds__(256) void k_scan3(int* __restrict__ off,
                                               const int* __restrict__ boff) {
    int b = blockIdx.x, t = threadIdx.x;
    int i = b * 256 + t;
    if (i < N_NODES) off[i] += boff[b];
}

// ---------------------------------------------------------------- gcursor init (bucket bases)
__global__ __launch_bounds__(256) void k_ginit(const int* __restrict__ off,
                                               int* __restrict__ gcursor) {
    int t = threadIdx.x;
    if (t < NBUCK) gcursor[t] = off[t * 256];
}

// ---------------------------------------------------------------- pass 1: LDS-staged bucket binning
__global__ __launch_bounds__(256) void k_bucket(const int* __restrict__ src,
                                                const int* __restrict__ dst,
                                                int* __restrict__ gcursor,
                                                unsigned long long* __restrict__ pairs) {
    __shared__ int lcount[256];
    __shared__ int lstart[256];
    __shared__ int lresv[256];
    __shared__ unsigned long long stage[P1_CHUNK];   // 16 KB
    int t = threadIdx.x;
    int base = blockIdx.x * P1_CHUNK;
    int cnt = N_EDGES - base; if (cnt > P1_CHUNK) cnt = P1_CHUNK;

    lcount[t] = 0;
    __syncthreads();

    int my_s[P1_EPT], my_d[P1_EPT], my_b[P1_EPT];
#pragma unroll
    for (int j = 0; j < P1_EPT; ++j) {
        int idx = t + j * 256;
        if (idx < cnt) {
            my_s[j] = src[base + idx];
            my_d[j] = dst[base + idx];
            my_b[j] = my_d[j] >> 8;
            atomicAdd(&lcount[my_b[j]], 1);
        } else my_b[j] = -1;
    }
    __syncthreads();

    int v = lcount[t];
    lstart[t] = v;
    __syncthreads();
#pragma unroll
    for (int d = 1; d < 256; d <<= 1) {
        int nv = (t >= d) ? lstart[t - d] : 0;
        __syncthreads();
        lstart[t] += nv;
        __syncthreads();
    }
    int excl = lstart[t] - v;
    __syncthreads();
    lstart[t] = excl;
    lresv[t] = (t < NBUCK && v > 0) ? atomicAdd(&gcursor[t], v) : 0;
    lcount[t] = 0;
    __syncthreads();

#pragma unroll
    for (int j = 0; j < P1_EPT; ++j) {
        if (my_b[j] >= 0) {
            int lpos = lstart[my_b[j]] + atomicAdd(&lcount[my_b[j]], 1);
            stage[lpos] = ((unsigned long long)(unsigned)my_d[j] << 32) | (unsigned)my_s[j];
        }
    }
    __syncthreads();

    for (int sl = t; sl < cnt; sl += 256) {
        unsigned long long pr = stage[sl];
        int d_ = (int)(pr >> 32);
        int b_ = d_ >> 8;
        int g = lresv[b_] + (sl - lstart[b_]);
        pairs[g] = pr;
    }
}

// ---------------------------------------------------------------- pass 2: bucket -> final CSR
__global__ __launch_bounds__(256) void k_csr(const unsigned long long* __restrict__ pairs,
                                             const int* __restrict__ off,
                                             int* __restrict__ src_s) {
    __shared__ int cur[256];
    int b = blockIdx.x, t = threadIdx.x;
    int nb0 = b * 256;
    int nb1 = nb0 + 256; if (nb1 > N_NODES) nb1 = N_NODES;
    int e0 = off[nb0], e1 = off[nb1];
    cur[t] = 0;
    __syncthreads();
    for (int e = e0 + t; e < e1; e += 256) {
        unsigned long long pr = pairs[e];
        int d_ = (int)(pr >> 32);
        int s_ = (int)(pr & 0xffffffffu);
        int pos = off[d_] + atomicAdd(&cur[d_ & 255], 1);
        src_s[pos] = s_;
    }
}

// ---------------------------------------------------------------- fused 4-matrix MFMA GEMM
// q -> bf16; k,v -> fp8 e4m3 interleaved [node][k128B|v128B]; skip -> bf16.
// Epilogue transposes acc through wave-private LDS -> wide (16B) stores.
__global__ __launch_bounds__(256) void k_gemm_fused(
    const __bf16* __restrict__ Xb,
    const __bf16* __restrict__ Wq, const __bf16* __restrict__ Wk,
    const __bf16* __restrict__ Wv, const __bf16* __restrict__ Wsk,
    const float* __restrict__ Bq, const float* __restrict__ Bk,
    const float* __restrict__ Bv, const float* __restrict__ Bs,
    __bf16* __restrict__ Oq, unsigned char* __restrict__ Okv,
    __bf16* __restrict__ Osk) {
    __shared__ float lt[4][32][33];   // wave-private 32x32 transpose tiles (+pad)
    int t = threadIdx.x;
    int wsel = t >> 6, l = t & 63;
    int lo5 = l & 31, hi = l >> 5;
    int row0 = blockIdx.x * 32;

    const __bf16* W = (wsel == 0) ? Wq : (wsel == 1) ? Wk : (wsel == 2) ? Wv : Wsk;
    const float*  B = (wsel == 0) ? Bq : (wsel == 1) ? Bk : (wsel == 2) ? Bv : Bs;

    const bf16x8* arow = (const bf16x8*)(Xb + (size_t)(row0 + lo5) * DIM + hi * 8);
    bf16x8 a[8];
#pragma unroll
    for (int kt = 0; kt < 8; ++kt) a[kt] = arow[kt * 2];

    int rr = l >> 1, h = l & 1;         // readback: row rr, 16-col half h
    int grow = row0 + rr;
    bool rok = (grow < N_NODES);

#pragma unroll
    for (int ct = 0; ct < 4; ++ct) {
        int col0 = ct * 32;
        const bf16x8* brow = (const bf16x8*)(W + (size_t)(col0 + lo5) * DIM + hi * 8);
        f32x16 acc = {};
#pragma unroll
        for (int kt = 0; kt < 8; ++kt)
            acc = __builtin_amdgcn_mfma_f32_32x32x16_bf16(a[kt], brow[kt * 2], acc, 0, 0, 0);

        float bias = B[col0 + lo5];
#pragma unroll
        for (int r = 0; r < 16; ++r) {
            int rl = (r & 3) + 8 * (r >> 2) + 4 * hi;
            lt[wsel][rl][lo5] = acc[r] + bias;
        }
        __syncthreads();

        float vals[16];
#pragma unroll
        for (int j = 0; j < 16; ++j) vals[j] = lt[wsel][rr][h * 16 + j];

        if (rok) {
            int gcol = col0 + h * 16;
            if (wsel == 0 || wsel == 3) {
                __bf16* O = (wsel == 0) ? Oq : Osk;
                bf16x8 o0, o1;
#pragma unroll
                for (int j = 0; j < 8; ++j) { o0[j] = (__bf16)vals[j]; o1[j] = (__bf16)vals[8 + j]; }
                bf16x8* orow = (bf16x8*)(O + (size_t)grow * DIM + gcol);
                orow[0] = o0; orow[1] = o1;
            } else {
                int coff = (wsel == 2) ? 128 : 0;   // k at +0, v at +128 bytes
                uint4 pk = pack16_fp8(vals);
                *(uint4*)(Okv + (size_t)grow * 256 + coff + gcol) = pk;
            }
        }
        __syncthreads();   // protect LDS tile before next ct overwrites
    }
}

// ---------------------------------------------------------------- fused alpha + softmax + aggregate (+skip+relu)
// One node per WAVE; 4x16-lane groups, 2-edge unroll, fp8 k/v via packed HW cvt,
// packed f32 math, no-max softmax.
__global__ __launch_bounds__(256) void k_edge_fused(const __bf16* __restrict__ q,
                                                    const unsigned char* __restrict__ kv,
                                                    const __bf16* __restrict__ skip,
                                                    const int* __restrict__ src_s,
                                                    const int* __restrict__ off,
                                                    float* __restrict__ xout,
                                                    __bf16* __restrict__ xb,
                                                    int wf32) {
    int t = threadIdx.x;
    int wave = t >> 6, l = t & 63;
    int n = blockIdx.x * 4 + wave;               // 50000 = 12500 * 4
    if (n >= N_NODES) return;
    int g = l >> 4, gl = l & 15;                 // 4 groups of 16 lanes
    int start = off[n], end = off[n + 1];

    const float S = 0.08838834764831845f;        // 1/sqrt(128), folded into q
    f32x2 qf[4];
    {
        bf16x8 qv = *(const bf16x8*)(q + (size_t)n * DIM + gl * 8);
#pragma unroll
        for (int j = 0; j < 4; ++j) {
            f32x2 r;
            r[0] = (float)qv[2 * j] * S;
            r[1] = (float)qv[2 * j + 1] * S;
            qf[j] = r;
        }
    }

    float denom = 0.f;
    f32x2 facc[4] = {};

    for (int e = start + g; e < end; e += 8) {   // this group's edges, 2 per iter
        int s0 = src_s[e];
        bool h1 = (e + 4 < end);
        int s1 = h1 ? src_s[e + 4] : s0;         // dummy (w1 forced to 0)
        const unsigned char* r0 = kv + (size_t)s0 * 256 + gl * 8;
        const unsigned char* r1 = kv + (size_t)s1 * 256 + gl * 8;
        U8 k0u, k1u, v0u, v1u;
        k0u.u = *(const uint2*)(r0);
        k1u.u = *(const uint2*)(r1);
        v0u.u = *(const uint2*)(r0 + 128);
        v1u.u = *(const uint2*)(r1 + 128);

        f32x2 k0f[4], k1f[4];
        cvt8_pk(k0u, k0f);
        cvt8_pk(k1u, k1f);
        f32x2 d0 = qf[0] * k0f[0];
        f32x2 d1 = qf[0] * k1f[0];
        d0 += qf[1] * k0f[1];  d1 += qf[1] * k1f[1];
        d0 += qf[2] * k0f[2];  d1 += qf[2] * k1f[2];
        d0 += qf[3] * k0f[3];  d1 += qf[3] * k1f[3];
        float p0 = d0[0] + d0[1];
        float p1 = d1[0] + d1[1];
        p0 += __shfl_xor(p0, 8, 16);  p1 += __shfl_xor(p1, 8, 16);
        p0 += __shfl_xor(p0, 4, 16);  p1 += __shfl_xor(p1, 4, 16);
        p0 += __shfl_xor(p0, 2, 16);  p1 += __shfl_xor(p1, 2, 16);
        p0 += __shfl_xor(p0, 1, 16);  p1 += __shfl_xor(p1, 1, 16);
        p0 = fminf(p0, 80.f);                    // overflow insurance only
        p1 = h1 ? fminf(p1, 80.f) : -INFINITY;

        float w0 = __expf(p0);
        float w1 = __expf(p1);                   // exp(-inf) = 0 kills the tail slot
        denom += w0 + w1;

        f32x2 v0f[4], v1f[4];
        cvt8_pk(v0u, v0f);
        cvt8_pk(v1u, v1f);
        f32x2 w02; w02[0] = w0; w02[1] = w0;
        f32x2 w12; w12[0] = w1; w12[1] = w1;
#pragma unroll
        for (int j = 0; j < 4; ++j)
            facc[j] += w02 * v0f[j] + w12 * v1f[j];
    }

    // merge the 4 groups: plain adds
#pragma unroll
    for (int dlt = 16; dlt <= 32; dlt <<= 1) {
        denom += __shfl_xor(denom, dlt, 64);
#pragma unroll
        for (int j = 0; j < 4; ++j) {
            f32x2 o;
            o[0] = __shfl_xor(facc[j][0], dlt, 64);
            o[1] = __shfl_xor(facc[j][1], dlt, 64);
            facc[j] += o;
        }
    }
    float inv = (denom > 0.f) ? 1.f / denom : 0.f;

    if (g == 0) {
        bf16x8 sk = *(const bf16x8*)(skip + (size_t)n * DIM + gl * 8);
        float o[8];
        bf16x8 ob;
#pragma unroll
        for (int j = 0; j < 8; ++j) {
            float f = facc[j >> 1][j & 1];
            float val = fmaxf((float)sk[j] + f * inv, 0.f);
            o[j] = val; ob[j] = (__bf16)val;
        }
        if (wf32) {
            float* xrow = xout + (size_t)n * DIM + gl * 8;
            *(float4*)(xrow)     = make_float4(o[0], o[1], o[2], o[3]);
            *(float4*)(xrow + 4) = make_float4(o[4], o[5], o[6], o[7]);
        }
        *(bf16x8*)(xb + (size_t)n * DIM + gl * 8) = ob;
    }
}

// ---------------------------------------------------------------- mean pool
__global__ __launch_bounds__(256) void k_pool(const float* __restrict__ x,
                                              const int* __restrict__ batch,
                                              float* __restrict__ out) {
    __shared__ float sacc[4][DIM];
    int g = blockIdx.x;
    int t = threadIdx.x;
    int w = t >> 6, l = t & 63;
    int lo = 0, hi = N_NODES;
    while (lo < hi) { int mid = (lo + hi) >> 1; if (batch[mid] < g) lo = mid + 1; else hi = mid; }
    int s0 = lo;
    hi = N_NODES;
    while (lo < hi) { int mid = (lo + hi) >> 1; if (batch[mid] < g + 1) lo = mid + 1; else hi = mid; }
    int s1 = lo;
    float a0 = 0.f, a1 = 0.f;
    for (int n = s0 + w; n < s1; n += 4) {
        float2 xr = *(const float2*)(x + (size_t)n * DIM + l * 2);
        a0 += xr.x; a1 += xr.y;
    }
    sacc[w][l * 2] = a0; sacc[w][l * 2 + 1] = a1;
    __syncthreads();
    if (t < DIM) {
        float s = sacc[0][t] + sacc[1][t] + sacc[2][t] + sacc[3][t];
        int cnt = s1 - s0;
        out[(size_t)g * DIM + t] = s / (float)((cnt > 0) ? cnt : 1);
    }
}

// ----------------------------------------------------------------
extern "C" void kernel_launch(void* const* d_in, const int* in_sizes, int n_in,
                              void* d_out, int out_size, void* d_ws, size_t ws_size,
                              hipStream_t stream) {
    const float* x0   = (const float*)d_in[0];
    const int*  eidx  = (const int*)d_in[1];
    const int*  batch = (const int*)d_in[2];
    const float* Wq = (const float*)d_in[3];
    const float* bq = (const float*)d_in[4];
    const float* Wk = (const float*)d_in[5];
    const float* bk = (const float*)d_in[6];
    const float* Wv = (const float*)d_in[7];
    const float* bv = (const float*)d_in[8];
    const float* Ws = (const float*)d_in[9];
    const float* bs = (const float*)d_in[10];
    float* out = (float*)d_out;

    const int* src = eidx;
    const int* dst = eidx + N_EDGES;

    char* ws = (char*)d_ws;
    size_t p = 0;
    auto alloc = [&](size_t bytes) -> void* {
        void* r = ws + p;
        p = (p + bytes + 255) & ~(size_t)255;
        return r;
    };
    int*    off    = (int*)alloc((N_NODES + 1) * sizeof(int));
    int*    cnt    = (int*)alloc(N_NODES * sizeof(int));
    int*    bsum   = (int*)alloc(256 * sizeof(int));
    int*    boff   = (int*)alloc(256 * sizeof(int));
    int*    gcur   = (int*)alloc(256 * sizeof(int));
    int*    src_s  = (int*)alloc(N_EDGES * sizeof(int));
    unsigned long long* prs = (unsigned long long*)alloc((size_t)N_EDGES * 8);
    __bf16* Xb     = (__bf16*)alloc((size_t)N_NODES * DIM * sizeof(__bf16));
    __bf16* qb     = (__bf16*)alloc((size_t)N_NODES * DIM * sizeof(__bf16));
    unsigned char* kvb = (unsigned char*)alloc((size_t)N_NODES * 256);
    __bf16* skb    = (__bf16*)alloc((size_t)N_NODES * DIM * sizeof(__bf16));
    float*  s1     = (float*)alloc((size_t)N_NODES * DIM * sizeof(float));
    __bf16* Wqb    = (__bf16*)alloc((size_t)NLAYERS * DIM * DIM * sizeof(__bf16));
    __bf16* Wkb    = (__bf16*)alloc((size_t)NLAYERS * DIM * DIM * sizeof(__bf16));
    __bf16* Wvb    = (__bf16*)alloc((size_t)NLAYERS * DIM * DIM * sizeof(__bf16));
    __bf16* Wsb    = (__bf16*)alloc((size_t)NLAYERS * DIM * DIM * sizeof(__bf16));

    // ---- casts
    {
        int nx = N_NODES * DIM;
        k_cast<<<(nx / 8 + 255) / 256, 256, 0, stream>>>(x0, Xb, nx);
        int nw = NLAYERS * DIM * DIM;
        dim3 gw((nw / 8 + 255) / 256, 4);
        k_cast4<<<gw, 256, 0, stream>>>(Wq, Wk, Wv, Ws, Wqb, Wkb, Wvb, Wsb, nw);
    }

    // ---- build CSR (degree -> scan -> LDS-staged 2-pass bucket sort)
    hipMemsetAsync(cnt, 0, N_NODES * sizeof(int), stream);
    k_degree<<<(N_EDGES + 255) / 256, 256, 0, stream>>>(dst, cnt);
    k_scan1<<<SCAN_NB, 256, 0, stream>>>(cnt, off, bsum);
    k_scan2<<<1, 256, 0, stream>>>(bsum, boff, off + N_NODES);
    k_scan3<<<SCAN_NB, 256, 0, stream>>>(off, boff);
    k_ginit<<<1, 256, 0, stream>>>(off, gcur);
    k_bucket<<<P1_NB, 256, 0, stream>>>(src, dst, gcur, prs);
    k_csr<<<NBUCK, 256, 0, stream>>>(prs, off, src_s);

    // ---- layers
    for (int l = 0; l < NLAYERS; ++l) {
        const __bf16* wq = Wqb + (size_t)l * DIM * DIM;
        const __bf16* wk = Wkb + (size_t)l * DIM * DIM;
        const __bf16* wv = Wvb + (size_t)l * DIM * DIM;
        const __bf16* wsk = Wsb + (size_t)l * DIM * DIM;
        const float* biq = bq + (size_t)l * DIM;
        const float* bik = bk + (size_t)l * DIM;
        const float* biv = bv + (size_t)l * DIM;
        const float* bis = bs + (size_t)l * DIM;

        k_gemm_fused<<<(N_NODES + 31) / 32, 256, 0, stream>>>(Xb, wq, wk, wv, wsk,
                                                              biq, bik, biv, bis,
                                                              qb, kvb, skb);
        int wf32 = (l == NLAYERS - 1) ? 1 : 0;
        k_edge_fused<<<(N_NODES + 3) / 4, 256, 0, stream>>>(qb, kvb, skb, src_s, off,
                                                            s1, Xb, wf32);
    }

    // ---- mean pool
    k_pool<<<NGRAPH, 256, 0, stream>>>(s1, batch, out);
}